// Round 8
// baseline (743.779 us; speedup 1.0000x reference)
//
#include <hip/hip_runtime.h>
#include <cstdint>
#include <cstdio>

typedef unsigned short u16;
typedef __attribute__((ext_vector_type(8))) short s8v;
typedef __attribute__((ext_vector_type(4))) float f4v;
typedef __attribute__((ext_vector_type(4))) unsigned short u16x4;
typedef const __attribute__((address_space(1))) void* gas_p;
typedef __attribute__((address_space(3))) void* las_p;

#define DEV __device__ __forceinline__

static constexpr float SCALE_ = 0.125f;             // 1/sqrt(64)
static constexpr float RES_SCALE_ = 0.7071067811865475f;
static constexpr float EPS_ = 1e-5f;

DEV u16 f2bf(float f) {
  uint32_t u = __float_as_uint(f);
  u += 0x7fffu + ((u >> 16) & 1u);
  return (u16)(u >> 16);
}
DEV float bf2f(u16 h) { return __uint_as_float(((uint32_t)h) << 16); }

DEV f4v mfma16(s8v a, s8v b, f4v c) {
  return __builtin_amdgcn_mfma_f32_16x16x32_bf16(a, b, c, 0, 0, 0);
}

#define WAITVM4 asm volatile("s_waitcnt vmcnt(4)" ::: "memory")
#define WAITVM0 asm volatile("s_waitcnt vmcnt(0)" ::: "memory")
#define SCHEDB  __builtin_amdgcn_sched_barrier(0)
#define BAR     __builtin_amdgcn_s_barrier()

// ---------------- utility ----------------

__global__ void k_zero(float* __restrict__ p, long n) {
  long i = (long)blockIdx.x * blockDim.x + threadIdx.x;
  long stride = (long)gridDim.x * blockDim.x;
  for (; i < n; i += stride) p[i] = 0.f;
}

// ---------------- prep mega-kernel helpers ----------------

DEV void dev_cvt(const float* __restrict__ in, u16* __restrict__ out, long n4,
                 int bid, int nblocks) {
  long i = (long)bid * 256 + threadIdx.x;
  long stride = (long)nblocks * 256;
  for (; i < n4; i += stride) {
    f4v v = *(const f4v*)&in[i * 4];
    u16x4 o;
    o.x = f2bf(v.x); o.y = f2bf(v.y); o.z = f2bf(v.z); o.w = f2bf(v.w);
    *(u16x4*)&out[i * 4] = o;
  }
}

// in: (K x N) f32 row-major -> out: (N x K) bf16 row-major. K,N multiples of 64.
DEV void dev_transpose(const float* __restrict__ in, u16* __restrict__ out,
                       int K, int N, int bx, int by, float tile[64][65]) {
  int kb = bx * 64, nb = by * 64;
  for (int i = threadIdx.x; i < 4096; i += 256) {
    int r = i >> 6, c = i & 63;
    tile[r][c] = in[(long)(kb + r) * N + nb + c];
  }
  __syncthreads();
  for (int i = threadIdx.x; i < 4096; i += 256) {
    int c = i >> 6, r = i & 63;
    out[(long)(nb + c) * K + kb + r] = f2bf(tile[r][c]);
  }
}

// aV (H,T,S,dh) f32 -> aVt (H,T,dh,S) bf16, one (h,t) per block
DEV void dev_avt(const float* __restrict__ aV, u16* __restrict__ aVt, int ht,
                 float tile[64][65]) {
  const float* src = aV + (long)ht * 4096;
  for (int i = threadIdx.x; i < 4096; i += 256) {
    int s = i >> 6, d = i & 63;
    tile[s][d] = src[i];
  }
  __syncthreads();
  u16* dst = aVt + (long)ht * 4096;
  for (int i = threadIdx.x; i < 4096; i += 256) {
    int d = i >> 6, s = i & 63;
    dst[i] = f2bf(tile[s][d]);
  }
}

// One kernel for all independent input-preprocessing work (saves ~12 launch gaps).
__launch_bounds__(256)
__global__ void k_prep(const float* __restrict__ x, u16* __restrict__ xbf,
                       const float* __restrict__ Wq, const float* __restrict__ Wk,
                       const float* __restrict__ Wv, const float* __restrict__ Wo,
                       u16* __restrict__ Wqkvt, u16* __restrict__ Wot,
                       const float* __restrict__ ph_w, u16* __restrict__ phwt,
                       const float* __restrict__ shw, u16* __restrict__ swt,
                       const float* __restrict__ pg_w, u16* __restrict__ pgwT,
                       const float* __restrict__ pt_w, u16* __restrict__ ptwT,
                       const float* __restrict__ aK, u16* __restrict__ aKb,
                       const float* __restrict__ aQ, u16* __restrict__ aQb,
                       const float* __restrict__ aV, u16* __restrict__ aVt,
                       const float* __restrict__ sb, float* __restrict__ extra) {
  __shared__ float tile[64][65];
  int b = blockIdx.x;
  if (b < 2048) { dev_cvt(x, xbf, 8388608, b, 2048); return; }
  b -= 2048;
  if (b < 1024) {  // 4x 1024x1024 weight transposes, 256 blocks each
    const float* src = (b < 256) ? Wq : (b < 512) ? Wk : (b < 768) ? Wv : Wo;
    u16* dst = (b < 256) ? Wqkvt : (b < 512) ? (Wqkvt + 1048576)
             : (b < 768) ? (Wqkvt + 2097152) : Wot;
    int id = b & 255;
    dev_transpose(src, dst, 1024, 1024, id & 15, id >> 4, tile);
    return;
  }
  b -= 1024;
  if (b < 256) { dev_transpose(ph_w, phwt, 256, 4096, b & 3, b >> 2, tile); return; }
  b -= 256;
  if (b < 256) { dev_transpose(shw, swt, 256, 4096, b & 3, b >> 2, tile); return; }
  b -= 256;
  if (b < 128) { dev_transpose(pg_w, pgwT, 2048, 256, b & 31, b >> 5, tile); return; }
  b -= 128;
  if (b < 128) {  // pt_w (1024 x 32) -> ptwT (32 x 1024)
    int idx = b * 256 + threadIdx.x;
    int n = idx >> 10, k = idx & 1023;
    ptwT[idx] = f2bf(pt_w[k * 32 + n]);
    return;
  }
  b -= 128;
  if (b < 512) { dev_cvt(aK, aKb, 1048576, b, 512); return; }
  b -= 512;
  if (b < 512) { dev_cvt(aQ, aQb, 1048576, b, 512); return; }
  b -= 512;
  if (b < 1024) { dev_avt(aV, aVt, b, tile); return; }
  b -= 1024;
  {  // extra[h*4096+t*64+s] = sb + SCALE * sum_d aQ*aK   (256 blocks)
    int idx = b * 256 + threadIdx.x;
    const float* q = aQ + (long)idx * 64;
    const float* k = aK + (long)idx * 64;
    float acc = 0.f;
#pragma unroll 8
    for (int d = 0; d < 64; d++) acc += q[d] * k[d];
    extra[idx] = sb[idx] + acc * SCALE_;
  }
}

// ---------------- 256x256 MFMA GEMM (16x16x32), pipelined, 5 barriers/K-tile ----
// C = A(MxK,bf16) * Bt(NxK,bf16)^T.  BK=64, 512 threads = 8 waves (2Mx4N),
// 128 KiB LDS double-buffer, global_load_lds staging with pre-swizzled SOURCE,
// linear LDS dest, swizzled ds_read.  [16x16x32 fragment pattern: measured 0
// LDS bank conflicts; 32x32x16 was 1.9e7 — do not convert.]
// Phase order per K-tile: Q00(Ah0*B01) Q01(Ah0*B23) Q10(Ah1*B01) Q11(Ah1*B23).
// Barrier schedule: pre-MFMA barrier every phase, post-MFMA barrier ONLY in P1
// (publishes b23(t)-read completion before P2's GLOADB overwrite); boundary
// vmcnt(4)+BAR in P3.  Hazard audit in round-2 notes.
// EPI 0: bf16 store. 2: bf16 +aux[(row&15)*4096|col]. 3: f32 (v+aux[col])*RES_SCALE.
template <int EPI>
__launch_bounds__(512)
__global__ void k_gemm256(const u16* __restrict__ A, const u16* __restrict__ Bt,
                          void* __restrict__ Cv, const float* __restrict__ aux,
                          int M, int N, int K) {
  __shared__ u16 lds[65536];  // A: [0,32768) ; B: [32768,65536). half=8192 elems.

  const int nwg = gridDim.x;
  int wg = blockIdx.x;
  if ((nwg & 7) == 0) wg = (wg & 7) * (nwg >> 3) + (wg >> 3);  // XCD swizzle
  const int ntiles = N >> 8;
  const int mt = wg / ntiles, ntb = wg % ntiles;

  const int tid = threadIdx.x;
  const int lane = tid & 63, w = tid >> 6;
  const int wrB = (w >> 2) * 128, wcB = (w & 3) * 64;
  const int lr = lane & 15, lg = lane >> 4;
  const int hA = w >> 2;             // wave's A half (0/1)
  const int hB = (w & 3) >> 1;       // wave's B half
  const int rB0 = (w & 1) * 64;      // wave's B row base within half
  const int xs0 = ((lg) ^ (lr & 7)) << 3;       // frag slot elem offset, ks=0
  const int xs1 = ((4 + lg) ^ (lr & 7)) << 3;   // ks=1
  const int nt = K >> 6;

  const int sr = tid >> 3;
  const int sslot = (tid & 7) ^ (sr & 7);

  // hoisted staging source pointers (per-thread row base + swizzled slot)
  const u16* aSrc = A + (long)(mt * 256 + sr) * K + sslot * 8;
  const u16* bSrc = Bt + (long)(ntb * 256 + sr) * K + sslot * 8;
  const long h128 = (long)128 * K;
  const long r64 = (long)64 * K;

#define GLOADA(tile, h)                                                          \
  do {                                                                           \
    const int bu_ = (tile) & 1;                                                  \
    const long o_ = (long)(tile) * 64 + (h) * h128;                              \
    __builtin_amdgcn_global_load_lds((gas_p)(aSrc + o_), (las_p)&lds[(bu_ * 2 + (h)) * 8192 + w * 512], 16, 0, 0); \
    __builtin_amdgcn_global_load_lds((gas_p)(aSrc + o_ + r64), (las_p)&lds[(bu_ * 2 + (h)) * 8192 + 4096 + w * 512], 16, 0, 0); \
  } while (0)

#define GLOADB(tile, h)                                                          \
  do {                                                                           \
    const int bu_ = (tile) & 1;                                                  \
    const long o_ = (long)(tile) * 64 + (h) * h128;                              \
    __builtin_amdgcn_global_load_lds((gas_p)(bSrc + o_), (las_p)&lds[32768 + (bu_ * 2 + (h)) * 8192 + w * 512], 16, 0, 0); \
    __builtin_amdgcn_global_load_lds((gas_p)(bSrc + o_ + r64), (las_p)&lds[32768 + (bu_ * 2 + (h)) * 8192 + 4096 + w * 512], 16, 0, 0); \
  } while (0)

  f4v acc[8][4];
#pragma unroll
  for (int mi = 0; mi < 8; mi++)
#pragma unroll
    for (int ni = 0; ni < 4; ni++) acc[mi][ni] = (f4v){0.f, 0.f, 0.f, 0.f};

  // ---- prologue: tile0 (A+B) and tile1 (B) staged, drained ----
  GLOADA(0, 0); GLOADA(0, 1);
  GLOADB(0, 0); GLOADB(0, 1);
  {
    const int t1 = (nt > 1) ? 1 : 0;
    GLOADB(t1, 0); GLOADB(t1, 1);
  }
  WAITVM0;
  BAR;

  s8v AF[4][2], b01[2][2], b23[2][2];

  // prologue fragment preload: Ah0(tile0) + B01(tile0), parity 0
  {
    const int aB0 = hA * 8192;
    const int bB0 = 32768 + hB * 8192;
#pragma unroll
    for (int mi = 0; mi < 4; mi++) {
      const int ro = (mi * 16 + lr) * 64;
      AF[mi][0] = *(const s8v*)&lds[aB0 + ro + xs0];
      AF[mi][1] = *(const s8v*)&lds[aB0 + ro + xs1];
    }
#pragma unroll
    for (int ni = 0; ni < 2; ni++) {
      const int ro = (rB0 + ni * 16 + lr) * 64;
      b01[ni][0] = *(const s8v*)&lds[bB0 + ro + xs0];
      b01[ni][1] = *(const s8v*)&lds[bB0 + ro + xs1];
    }
  }
  SCHEDB;

  for (int t = 0; t < nt; ++t) {
    const int p = t & 1, q = p ^ 1;
    const int aN = (t + 1 < nt) ? t + 1 : nt - 1;
    const int bN = (t + 2 < nt) ? t + 2 : nt - 1;
    const int aBase = (p * 2 + hA) * 8192;
    const int bBase = 32768 + (p * 2 + hB) * 8192;
    const int aBaseN = (q * 2 + hA) * 8192;
    const int bBaseN = 32768 + (q * 2 + hB) * 8192;

    // ===== P0: Q00 = Ah0 x B01 ; prefetch b23(t) ; stage A(t+1,h0) =====
#pragma unroll
    for (int ni = 0; ni < 2; ni++) {
      const int ro = (rB0 + (2 + ni) * 16 + lr) * 64;
      b23[ni][0] = *(const s8v*)&lds[bBase + ro + xs0];
      b23[ni][1] = *(const s8v*)&lds[bBase + ro + xs1];
    }
    SCHEDB;
    GLOADA(aN, 0);
    BAR;
    __builtin_amdgcn_s_setprio(1);
#pragma unroll
    for (int mi = 0; mi < 4; mi++)
#pragma unroll
      for (int ks = 0; ks < 2; ks++)
#pragma unroll
        for (int ni = 0; ni < 2; ni++)
          acc[mi][ni] = mfma16(AF[mi][ks], b01[ni][ks], acc[mi][ni]);
    __builtin_amdgcn_s_setprio(0);

    // ===== P1: Q01 = Ah0 x B23 ; interleaved reload AF<-Ah1(t) ; stage A(t+1,h1) =====
    GLOADA(aN, 1);
    BAR;
    __builtin_amdgcn_s_setprio(1);
#pragma unroll
    for (int mi = 0; mi < 4; mi++) {
#pragma unroll
      for (int ks = 0; ks < 2; ks++)
#pragma unroll
        for (int ni = 0; ni < 2; ni++)
          acc[mi][2 + ni] = mfma16(AF[mi][ks], b23[ni][ks], acc[mi][2 + ni]);
      const int ro = (64 + mi * 16 + lr) * 64;
      AF[mi][0] = *(const s8v*)&lds[aBase + ro + xs0];
      AF[mi][1] = *(const s8v*)&lds[aBase + ro + xs1];
      SCHEDB;
    }
    __builtin_amdgcn_s_setprio(0);
    BAR;  // LOAD-BEARING: publishes completion of b23(t) reads (first consumed
          // in this phase) before P2's GLOADB overwrites that region.

    // ===== P2: Q10 = Ah1 x B01 ; stage B(t+2,h0) =====
    GLOADB(bN, 0);
    BAR;
    __builtin_amdgcn_s_setprio(1);
#pragma unroll
    for (int mi = 0; mi < 4; mi++)
#pragma unroll
      for (int ks = 0; ks < 2; ks++)
#pragma unroll
        for (int ni = 0; ni < 2; ni++)
          acc[4 + mi][ni] = mfma16(AF[mi][ks], b01[ni][ks], acc[4 + mi][ni]);
    __builtin_amdgcn_s_setprio(0);

    // ===== P3: Q11 = Ah1 x B23 ; boundary vmcnt(4)+BAR ; prefetch b01(t+1) ;
    //           interleaved reload AF<-Ah0(t+1) ; stage B(t+2,h1) =====
    GLOADB(bN, 1);
    WAITVM4;
    BAR;
#pragma unroll
    for (int ni = 0; ni < 2; ni++) {
      const int ro = (rB0 + ni * 16 + lr) * 64;
      b01[ni][0] = *(const s8v*)&lds[bBaseN + ro + xs0];
      b01[ni][1] = *(const s8v*)&lds[bBaseN + ro + xs1];
    }
    SCHEDB;
    __builtin_amdgcn_s_setprio(1);
#pragma unroll
    for (int mi = 0; mi < 4; mi++) {
#pragma unroll
      for (int ks = 0; ks < 2; ks++)
#pragma unroll
        for (int ni = 0; ni < 2; ni++)
          acc[4 + mi][2 + ni] = mfma16(AF[mi][ks], b23[ni][ks], acc[4 + mi][2 + ni]);
      const int ro = (mi * 16 + lr) * 64;
      AF[mi][0] = *(const s8v*)&lds[aBaseN + ro + xs0];
      AF[mi][1] = *(const s8v*)&lds[aBaseN + ro + xs1];
      SCHEDB;
    }
    __builtin_amdgcn_s_setprio(0);
  }
#undef GLOADA
#undef GLOADB

  // ---- epilogue ----
  const int rbase = mt * 256 + wrB + lg * 4;
  const int cbase = ntb * 256 + wcB + lr;
  if (EPI == 0) {
    u16* C = (u16*)Cv;
#pragma unroll
    for (int mi = 0; mi < 8; mi++)
#pragma unroll
      for (int ni = 0; ni < 4; ni++)
#pragma unroll
        for (int j = 0; j < 4; j++)
          C[(long)(rbase + mi * 16 + j) * N + (cbase + ni * 16)] = f2bf(acc[mi][ni][j]);
  } else if (EPI == 2) {
    u16* C = (u16*)Cv;
#pragma unroll
    for (int mi = 0; mi < 8; mi++)
#pragma unroll
      for (int ni = 0; ni < 4; ni++)
#pragma unroll
        for (int j = 0; j < 4; j++) {
          const int row = rbase + mi * 16 + j;
          const int col = cbase + ni * 16;
          C[(long)row * N + col] = f2bf(acc[mi][ni][j] + aux[((row & 15) << 12) | col]);
        }
  } else {
    float* C = (float*)Cv;
#pragma unroll
    for (int mi = 0; mi < 8; mi++)
#pragma unroll
      for (int ni = 0; ni < 4; ni++)
#pragma unroll
        for (int j = 0; j < 4; j++) {
          const int col = cbase + ni * 16;
          C[(long)(rbase + mi * 16 + j) * N + col] =
              (acc[mi][ni][j] + aux[col]) * RES_SCALE_;
        }
  }
}

// ---------------- generic 128x128 MFMA GEMM (small/medium shapes) ----------------
// EPI 1: f32 +bias[col].
template <int EPI>
__launch_bounds__(256)
__global__ void k_gemm(const u16* __restrict__ A, const u16* __restrict__ Bt,
                       void* __restrict__ Cv, const float* __restrict__ aux,
                       int M, int N, int K) {
  __shared__ u16 As[4096];
  __shared__ u16 Bs[4096];
  const int ntiles = N >> 7;
  const int mt = blockIdx.x / ntiles;
  const int nt = blockIdx.x % ntiles;
  const int tid = threadIdx.x;
  const int lane = tid & 63;
  const int w = tid >> 6;
  const int wr = w >> 1, wc = w & 1;
  const int lr = lane & 15, lg = lane >> 4;

  f4v acc[4][4];
#pragma unroll
  for (int m = 0; m < 4; m++)
#pragma unroll
    for (int n = 0; n < 4; n++) acc[m][n] = (f4v){0.f, 0.f, 0.f, 0.f};

  const u16* aSrc = A + (long)(mt * 128 + (tid >> 2)) * K + ((tid & 3) << 3);
  const u16* bSrc = Bt + (long)(nt * 128 + (tid >> 2)) * K + ((tid & 3) << 3);
  const long rowStep = (long)64 * K;

  const int kIters = K >> 5;
  for (int kb = 0; kb < kIters; kb++) {
    if (kb) __syncthreads();
    const u16* aP = aSrc + (kb << 5);
    const u16* bP = bSrc + (kb << 5);
    __builtin_amdgcn_global_load_lds((gas_p)aP, (las_p)&As[w * 512], 16, 0, 0);
    __builtin_amdgcn_global_load_lds((gas_p)(aP + rowStep), (las_p)&As[2048 + w * 512], 16, 0, 0);
    __builtin_amdgcn_global_load_lds((gas_p)bP, (las_p)&Bs[w * 512], 16, 0, 0);
    __builtin_amdgcn_global_load_lds((gas_p)(bP + rowStep), (las_p)&Bs[2048 + w * 512], 16, 0, 0);
    WAITVM0;
    __syncthreads();

    s8v af[4];
#pragma unroll
    for (int m = 0; m < 4; m++)
      af[m] = *(const s8v*)&As[(wr * 64 + m * 16 + lr) * 32 + (lg << 3)];
#pragma unroll
    for (int n = 0; n < 4; n++) {
      s8v bf = *(const s8v*)&Bs[(wc * 64 + n * 16 + lr) * 32 + (lg << 3)];
#pragma unroll
      for (int m = 0; m < 4; m++) acc[m][n] = mfma16(af[m], bf, acc[m][n]);
    }
  }

  const int rbase = mt * 128 + wr * 64 + lg * 4;
  const int cbase = nt * 128 + wc * 64 + lr;
  {
    float* C = (float*)Cv;
#pragma unroll
    for (int m = 0; m < 4; m++)
#pragma unroll
      for (int n = 0; n < 4; n++)
#pragma unroll
        for (int j = 0; j < 4; j++) {
          int row = rbase + m * 16 + j;
          int col = cbase + n * 16;
          C[(long)row * N + col] = acc[m][n][j] + aux[col];
        }
  }
}

// ---------------- smolgen MFMA layers ----------------

// z(32768x32 bf16) = xbf(32768x1024) @ ptwT(32x1024)^T + ptb
__launch_bounds__(256)
__global__ void k_smola_gemm(const u16* __restrict__ xbf, const u16* __restrict__ ptwT,
                             const float* __restrict__ ptb, u16* __restrict__ z) {
  const int rt = blockIdx.x;
  const int w = threadIdx.x >> 6, lane = threadIdx.x & 63;
  const int lr = lane & 15, lg = lane >> 4;
  const int row0 = rt * 64 + w * 16;
  f4v acc[2];
  acc[0] = (f4v){0.f, 0.f, 0.f, 0.f};
  acc[1] = (f4v){0.f, 0.f, 0.f, 0.f};
  const u16* aBase = xbf + (long)(row0 + lr) * 1024;
  const u16* bBase = ptwT + (long)lr * 1024;
#pragma unroll 4
  for (int k0 = 0; k0 < 1024; k0 += 32) {
    s8v a = *(const s8v*)&aBase[k0 + (lg << 3)];
#pragma unroll
    for (int n = 0; n < 2; n++) {
      s8v b = *(const s8v*)&bBase[(long)(n << 4) * 1024 + k0 + (lg << 3)];
      acc[n] = mfma16(a, b, acc[n]);
    }
  }
#pragma unroll
  for (int n = 0; n < 2; n++)
#pragma unroll
    for (int j = 0; j < 4; j++) {
      int col = (n << 4) + lr;
      z[(long)(row0 + lg * 4 + j) * 32 + col] = f2bf(acc[n][j] + ptb[col]);
    }
}

// Fused: uraw2 = z(512x2048) @ pgwT(256x2048)^T + pgb  ->  g = LN(silu(uraw2)).
// 32 blocks x 256 thr; wave w == old k_smolb_gemm block (rt=blockIdx, ct=w),
// LN loop == old k_ln2 per row (identical 64-lane shfl reduction) => bit-identical.
// (R5-verified: absmax unchanged with this fusion; R5's regression was traced to
// the P-layout/l23-order changes, both long since reverted.)
__launch_bounds__(256)
__global__ void k_smolb_ln(const u16* __restrict__ z, const u16* __restrict__ pgwT,
                           const float* __restrict__ pgb, const float* __restrict__ g1,
                           const float* __restrict__ b1, u16* __restrict__ g) {
  __shared__ float tile[16][260];
  const int rt = blockIdx.x;
  const int w = threadIdx.x >> 6, lane = threadIdx.x & 63;
  const int lr = lane & 15, lg = lane >> 4;
  f4v acc[4];
#pragma unroll
  for (int n = 0; n < 4; n++) acc[n] = (f4v){0.f, 0.f, 0.f, 0.f};
  const u16* aBase = z + (long)(rt * 16 + lr) * 2048;
  const u16* bBase = pgwT + (long)(w * 64 + lr) * 2048;
#pragma unroll 4
  for (int k0 = 0; k0 < 2048; k0 += 32) {
    s8v a = *(const s8v*)&aBase[k0 + (lg << 3)];
#pragma unroll
    for (int n = 0; n < 4; n++) {
      s8v b = *(const s8v*)&bBase[(long)(n << 4) * 2048 + k0 + (lg << 3)];
      acc[n] = mfma16(a, b, acc[n]);
    }
  }
#pragma unroll
  for (int n = 0; n < 4; n++)
#pragma unroll
    for (int j = 0; j < 4; j++) {
      int row = lg * 4 + j;
      int col = w * 64 + (n << 4) + lr;
      tile[row][col] = acc[n][j] + pgb[col];
    }
  __syncthreads();
  // LN: wave w handles rows w*4 .. w*4+3 (old k_ln2 math).
#pragma unroll
  for (int i = 0; i < 4; i++) {
    const int row = w * 4 + i;
    float v[4];
    float s = 0.f, q = 0.f;
#pragma unroll
    for (int j = 0; j < 4; j++) {
      float xx = tile[row][lane * 4 + j];
      v[j] = xx / (1.f + __expf(-xx));
      s += v[j]; q += v[j] * v[j];
    }
#pragma unroll
    for (int mk = 1; mk < 64; mk <<= 1) { s += __shfl_xor(s, mk); q += __shfl_xor(q, mk); }
    float mean = s * (1.f / 256.f);
    float var = q * (1.f / 256.f) - mean * mean;
    float rs = rsqrtf(var + EPS_);
    u16x4 o;
    o.x = f2bf((v[0] - mean) * rs * g1[lane * 4 + 0] + b1[lane * 4 + 0]);
    o.y = f2bf((v[1] - mean) * rs * g1[lane * 4 + 1] + b1[lane * 4 + 1]);
    o.z = f2bf((v[2] - mean) * rs * g1[lane * 4 + 2] + b1[lane * 4 + 2]);
    o.w = f2bf((v[3] - mean) * rs * g1[lane * 4 + 3] + b1[lane * 4 + 3]);
    *(u16x4*)&g[(long)(rt * 16 + row) * 256 + lane * 4] = o;
  }
}

// u = LN(silu(in)) per row of 256; in already has bias added. out bf16.
__launch_bounds__(64)
__global__ void k_ln2(const float* __restrict__ uraw, const float* __restrict__ g2,
                      const float* __restrict__ b2, u16* __restrict__ ubf) {
  const int row = blockIdx.x;
  const int lane = threadIdx.x;
  f4v x = *(const f4v*)&uraw[(long)row * 256 + lane * 4];
  float v[4];
  float s = 0.f, q = 0.f;
#pragma unroll
  for (int j = 0; j < 4; j++) {
    float xx = x[j];
    v[j] = xx / (1.f + __expf(-xx));
    s += v[j]; q += v[j] * v[j];
  }
#pragma unroll
  for (int mk = 1; mk < 64; mk <<= 1) { s += __shfl_xor(s, mk); q += __shfl_xor(q, mk); }
  float mean = s * (1.f / 256.f);
  float var = q * (1.f / 256.f) - mean * mean;
  float rs = rsqrtf(var + EPS_);
  u16x4 o;
  float o0 = (v[0] - mean) * rs * g2[lane * 4 + 0] + b2[lane * 4 + 0];
  float o1 = (v[1] - mean) * rs * g2[lane * 4 + 1] + b2[lane * 4 + 1];
  float o2 = (v[2] - mean) * rs * g2[lane * 4 + 2] + b2[lane * 4 + 2];
  float o3 = (v[3] - mean) * rs * g2[lane * 4 + 3] + b2[lane * 4 + 3];
  o.x = f2bf(o0); o.y = f2bf(o1); o.z = f2bf(o2); o.w = f2bf(o3);
  *(u16x4*)&ubf[(long)row * 256 + lane * 4] = o;
}

// ---------------- batched 64x64x64 MFMA kernels ----------------

// merged l2 + l3 (independent, same shape) — saves one launch gap.
__launch_bounds__(64)
__global__ void k_l23(const u16* __restrict__ qkv, const u16* __restrict__ aKb,
                      const u16* __restrict__ aQb, u16* __restrict__ l2b,
                      u16* __restrict__ l3a) {
  const int lane = threadIdx.x;
  const int lr = lane & 15, lg = lane >> 4;
  f4v acc[4][4];
#pragma unroll
  for (int m = 0; m < 4; m++)
#pragma unroll
    for (int n = 0; n < 4; n++) acc[m][n] = (f4v){0.f, 0.f, 0.f, 0.f};

  if (blockIdx.x < 8192) {
    const int bid = blockIdx.x;
    const int bt = bid & 7, t = (bid >> 3) & 63, h = bid >> 9;
    const u16* qb = qkv + (long)t * 3072 + h * 64;
    const u16* kb = aKb + ((long)h * 64 + t) * 4096;
#pragma unroll
    for (int ks = 0; ks < 2; ks++) {
      s8v a[4], bb[4];
#pragma unroll
      for (int m = 0; m < 4; m++) {
        int brow = bt * 64 + m * 16 + lr;
        a[m] = *(const s8v*)&qb[(long)brow * 196608 + ks * 32 + (lg << 3)];
      }
#pragma unroll
      for (int n = 0; n < 4; n++)
        bb[n] = *(const s8v*)&kb[(n * 16 + lr) * 64 + ks * 32 + (lg << 3)];
#pragma unroll
      for (int m = 0; m < 4; m++)
#pragma unroll
        for (int n = 0; n < 4; n++) acc[m][n] = mfma16(a[m], bb[n], acc[m][n]);
    }
    u16* dst = l2b + ((long)h * 64 + t) * 32768;  // + b*64 + s
#pragma unroll
    for (int m = 0; m < 4; m++)
#pragma unroll
      for (int n = 0; n < 4; n++)
#pragma unroll
        for (int j = 0; j < 4; j++) {
          int brow = bt * 64 + m * 16 + lg * 4 + j;
          int s = n * 16 + lr;
          dst[(long)brow * 64 + s] = f2bf(SCALE_ * acc[m][n][j]);
        }
  } else {
    const int bid = blockIdx.x - 8192;
    const int bt = bid & 7, s = (bid >> 3) & 63, h = bid >> 9;
    const u16* kb = qkv + (long)s * 3072 + 1024 + h * 64;
    const u16* qb = aQb + (long)h * 262144 + (long)s * 64;
#pragma unroll
    for (int ks = 0; ks < 2; ks++) {
      s8v a[4], bb[4];
#pragma unroll
      for (int m = 0; m < 4; m++) {
        int brow = bt * 64 + m * 16 + lr;
        a[m] = *(const s8v*)&kb[(long)brow * 196608 + ks * 32 + (lg << 3)];
      }
#pragma unroll
      for (int n = 0; n < 4; n++) {
        int tc = n * 16 + lr;
        bb[n] = *(const s8v*)&qb[(long)tc * 4096 + ks * 32 + (lg << 3)];
      }
#pragma unroll
      for (int m = 0; m < 4; m++)
#pragma unroll
        for (int n = 0; n < 4; n++) acc[m][n] = mfma16(a[m], bb[n], acc[m][n]);
    }
#pragma unroll
    for (int m = 0; m < 4; m++)
#pragma unroll
      for (int n = 0; n < 4; n++)
#pragma unroll
        for (int j = 0; j < 4; j++) {
          int brow = bt * 64 + m * 16 + lg * 4 + j;
          int tc = n * 16 + lr;
          long idx = (((long)brow * 16 + h) * 64 + s) * 64 + tc;
          l3a[idx] = f2bf(SCALE_ * acc[m][n][j]);
        }
  }
}

// out_heads[b,t,h,d] += sum_s attn[b,h,t,s]*aV[h,t,s,d];  grid h*512 + t*8 + bt
__launch_bounds__(64)
__global__ void k_c(const u16* __restrict__ attnb, const u16* __restrict__ aVt,
                    u16* __restrict__ outh) {
  const int bid = blockIdx.x;
  const int bt = bid & 7, t = (bid >> 3) & 63, h = bid >> 9;
  const int lane = threadIdx.x;
  const int lr = lane & 15, lg = lane >> 4;
  f4v acc[4][4];
#pragma unroll
  for (int m = 0; m < 4; m++)
#pragma unroll
    for (int n = 0; n < 4; n++) acc[m][n] = (f4v){0.f, 0.f, 0.f, 0.f};
  const u16* ab = attnb + ((long)h * 64 + t) * 64;      // + b*65536
  const u16* vb = aVt + ((long)h * 64 + t) * 4096;      // rows d, contiguous s
#pragma unroll
  for (int ks = 0; ks < 2; ks++) {
    s8v a[4], bb[4];
#pragma unroll
    for (int m = 0; m < 4; m++) {
      int brow = bt * 64 + m * 16 + lr;
      a[m] = *(const s8v*)&ab[(long)brow * 65536 + ks * 32 + (lg << 3)];
    }
#pragma unroll
    for (int n = 0; n < 4; n++)
      bb[n] = *(const s8v*)&vb[(n * 16 + lr) * 64 + ks * 32 + (lg << 3)];
#pragma unroll
    for (int m = 0; m < 4; m++)
#pragma unroll
      for (int n = 0; n < 4; n++) acc[m][n] = mfma16(a[m], bb[n], acc[m][n]);
  }
#pragma unroll
  for (int m = 0; m < 4; m++)
#pragma unroll
    for (int n = 0; n < 4; n++)
#pragma unroll
      for (int j = 0; j < 4; j++) {
        int brow = bt * 64 + m * 16 + lg * 4 + j;
        int d = n * 16 + lr;
        long idx = ((long)brow * 64 + t) * 1024 + h * 64 + d;
        outh[idx] = f2bf(bf2f(outh[idx]) + acc[m][n][j]);
      }
}

// ---------------- attention core: per (b,h) ----------------
// l3a slice staged COALESCED into Ps during the initial staging loop; the
// transposed [s][t] p-compute read comes from LDS (4x transaction amplification
// removed).  Pad 72 => 144B rows = 9x16B so staged s8v writes stay 16B-aligned;
// transposed u16x4 reads are 2-way bank-aliased (free).  Barrier count
// unchanged (first sync covers staging; pre-P-write sync protects Ps overwrite).
__launch_bounds__(256)
__global__ void k_attn(const u16* __restrict__ qkv, const u16* __restrict__ logits,
                       const u16* __restrict__ l2b, u16* __restrict__ l3a,
                       u16* __restrict__ outh) {
  __shared__ u16 Qs[64 * 72];
  __shared__ u16 Ks[64 * 72];
  __shared__ u16 Vt[64 * 72];
  __shared__ u16 Ps[64 * 72];   // staged l3a slice first, then P
  const int bh = blockIdx.x;
  const int b = bh >> 4, h = bh & 15;
  const int tid = threadIdx.x;
  const int lane = tid & 63, w = tid >> 6;
  const int lr = lane & 15, lg = lane >> 4;
  const u16* qbase = qkv + (long)b * 196608 + h * 64;
  const long base = (long)bh * 4096;

#pragma unroll
  for (int c = 0; c < 2; c++) {
    int flat = c * 2048 + tid * 8;
    int row = flat >> 6, k = flat & 63;
    const u16* src = &qbase[(long)row * 3072 + k];
    *(s8v*)&Qs[row * 72 + k] = *(const s8v*)(src);
    *(s8v*)&Ks[row * 72 + k] = *(const s8v*)(src + 1024);
    s8v v = *(const s8v*)(src + 2048);
#pragma unroll
    for (int j = 0; j < 8; j++) Vt[(k + j) * 72 + row] = (u16)v[j];
    // coalesced l3a staging: Ps[s][t] mirrors global [s-major] layout
    *(s8v*)&Ps[row * 72 + k] = *(const s8v*)&l3a[base + flat];
  }
  __syncthreads();

  f4v sacc[4];
#pragma unroll
  for (int n = 0; n < 4; n++) sacc[n] = (f4v){0.f, 0.f, 0.f, 0.f};
#pragma unroll
  for (int ks = 0; ks < 2; ks++) {
    s8v a = *(const s8v*)&Qs[(w * 16 + lr) * 72 + ks * 32 + (lg << 3)];
#pragma unroll
    for (int n = 0; n < 4; n++) {
      s8v bb = *(const s8v*)&Ks[(n * 16 + lr) * 72 + ks * 32 + (lg << 3)];
      sacc[n] = mfma16(a, bb, sacc[n]);
    }
  }

  const int r0 = w * 16 + lg * 4;
  float p[4][4];
#pragma unroll
  for (int n = 0; n < 4; n++) {
    int s = n * 16 + lr;
    u16x4 l3v = *(const u16x4*)&Ps[s * 72 + r0];   // LDS (staged l3a)
#pragma unroll
    for (int j = 0; j < 4; j++) {
      float l3f = bf2f(((const u16*)&l3v)[j]);
      float l2f = bf2f(l2b[(((long)h * 64 + r0 + j) * 512 + b) * 64 + s]);
      float lgf = bf2f(logits[base + (r0 + j) * 64 + s]);
      p[n][j] = sacc[n][j] * SCALE_ + lgf + l3f + l2f;
    }
  }
#pragma unroll
  for (int j = 0; j < 4; j++) {
    float m = fmaxf(fmaxf(p[0][j], p[1][j]), fmaxf(p[2][j], p[3][j]));
    m = fmaxf(m, __shfl_xor(m, 1));
    m = fmaxf(m, __shfl_xor(m, 2));
    m = fmaxf(m, __shfl_xor(m, 4));
    m = fmaxf(m, __shfl_xor(m, 8));
    float s0 = 0.f;
#pragma unroll
    for (int n = 0; n < 4; n++) { p[n][j] = __expf(p[n][j] - m); s0 += p[n][j]; }
    s0 += __shfl_xor(s0, 1);
    s0 += __shfl_xor(s0, 2);
    s0 += __shfl_xor(s0, 4);
    s0 += __shfl_xor(s0, 8);
    float inv = 1.f / s0;
#pragma unroll
    for (int n = 0; n < 4; n++) p[n][j] *= inv;
  }

  // All Ps-as-l3a reads complete in every thread past this barrier; safe to
  // overwrite Ps with P (and l3a global with P for k_c).
  __syncthreads();

#pragma unroll
  for (int n = 0; n < 4; n++) {
    int s = n * 16 + lr;
#pragma unroll
    for (int j = 0; j < 4; j++) {
      u16 pb = f2bf(p[n][j]);
      l3a[base + (r0 + j) * 64 + s] = pb;
      Ps[(r0 + j) * 72 + s] = pb;
    }
  }
  __syncthreads();

  f4v oacc[4];
#pragma unroll
  for (int n = 0; n < 4; n++) oacc[n] = (f4v){0.f, 0.f, 0.f, 0.f};
#pragma unroll
  for (int ks = 0; ks < 2; ks++) {
    s8v a = *(const s8v*)&Ps[(w * 16 + lr) * 72 + ks * 32 + (lg << 3)];
#pragma unroll
    for (int n = 0; n < 4; n++) {
      s8v vb = *(const s8v*)&Vt[(n * 16 + lr) * 72 + ks * 32 + (lg << 3)];
      oacc[n] = mfma16(a, vb, oacc[n]);
    }
  }
  u16* obase = outh + (long)b * 65536 + h * 64;
#pragma unroll
  for (int n = 0; n < 4; n++)
#pragma unroll
    for (int j = 0; j < 4; j++)
      obase[(long)(r0 + j) * 1024 + n * 16 + lr] = f2bf(oacc[n][j]);
}

// ---------------- launcher ----------------

extern "C" void kernel_launch(void* const* d_in, const int* in_sizes, int n_in,
                              void* d_out, int out_size, void* d_ws, size_t ws_size,
                              hipStream_t stream) {
  (void)in_sizes; (void)n_in;
  const float* x    = (const float*)d_in[0];
  const float* Wq   = (const float*)d_in[1];
  const float* Wk   = (const float*)d_in[2];
  const float* Wv   = (const float*)d_in[3];
  const float* Wo_w = (const float*)d_in[4];
  const float* Wo_b = (const float*)d_in[5];
  const float* sb   = (const float*)d_in[6];
  const float* aQ   = (const float*)d_in[7];
  const float* aK   = (const float*)d_in[8];
  const float* aV   = (const float*)d_in[9];
  const float* pt_w = (const float*)d_in[10];
  const float* pt_b = (const float*)d_in[11];
  const float* pg_w = (const float*)d_in[12];
  const float* pg_b = (const float*)d_in[13];
  const float* ph_w = (const float*)d_in[14];
  const float* ph_b = (const float*)d_in[15];
  const float* ln1g = (const float*)d_in[16];
  const float* ln1b = (const float*)d_in[17];
  const float* ln2g = (const float*)d_in[18];
  const float* ln2b = (const float*)d_in[19];
  const float* shw  = (const float*)d_in[20];

  char* wsp = (char*)d_ws;
  size_t off = 0;
  auto alloc = [&](size_t bytes) {
    void* p = wsp + off;
    off += (bytes + 255) & ~(size_t)255;
    return p;
  };
  u16*   xbf    = (u16*)alloc(33554432ull * 2);    // also reused as outh
  u16*   qkv    = (u16*)alloc(100663296ull * 2);   // 32768 x 3072
  u16*   logits = (u16*)alloc(33554432ull * 2);    // (B,H,T,S) bf16 (smolgen+extra)
  u16*   l3a    = (u16*)alloc(33554432ull * 2);    // l3 term, then attn probs
  u16*   l2b    = (u16*)alloc(33554432ull * 2);    // l2 term (h,t,b,s)
  u16*   Wqkvt  = (u16*)alloc(3145728ull * 2);     // 3072 x 1024
  u16*   Wot    = (u16*)alloc(1048576ull * 2);
  u16*   phwt   = (u16*)alloc(1048576ull * 2);     // 4096 x 256
  u16*   swt    = (u16*)alloc(1048576ull * 2);     // 4096 x 256
  u16*   aKb    = (u16*)alloc(4194304ull * 2);
  u16*   aQb    = (u16*)alloc(4194304ull * 2);
  u16*   aVt    = (u16*)alloc(4194304ull * 2);
  float* extra  = (float*)alloc(65536ull * 4);
  u16*   z      = (u16*)alloc(1048576ull * 2);     // 32768 x 32
  u16*   g      = (u16*)alloc(131072ull * 2);      // 512 x 256
  float* uraw   = (float*)alloc(2097152ull * 4);   // 512 x 4096
  u16*   ubf    = (u16*)alloc(2097152ull * 2);     // 8192 x 256
  u16*   ptwT   = (u16*)alloc(32768ull * 2);       // 32 x 1024
  u16*   pgwT   = (u16*)alloc(524288ull * 2);      // 256 x 2048
  u16*   outh   = xbf;                             // alias: xbf dead after smolgen A
  float* dout   = (float*)d_out;

  if (off > ws_size) {
    fprintf(stderr, "[kernel_launch] insufficient workspace: need %zu have %zu\n",
            off, ws_size);
    k_zero<<<2048, 256, 0, stream>>>(dout, (long)out_size);
    return;
  }

  // all independent input prep in one launch
  k_prep<<<6144, 256, 0, stream>>>(x, xbf, Wq, Wk, Wv, Wo_w, Wqkvt, Wot,
                                   ph_w, phwt, shw, swt, pg_w, pgwT, pt_w, ptwT,
                                   aK, aKb, aQ, aQb, aV, aVt, sb, extra);

  k_gemm256<0><<<1536, 512, 0, stream>>>(xbf, Wqkvt, qkv, nullptr, 32768, 3072, 1024);

  k_smola_gemm<<<512, 256, 0, stream>>>(xbf, ptwT, pt_b, z);
  k_smolb_ln<<<32, 256, 0, stream>>>(z, pgwT, pg_b, ln1g, ln1b, g);
  k_gemm<1><<<128, 256, 0, stream>>>(g, phwt, uraw, ph_b, 512, 4096, 256);
  k_ln2<<<8192, 64, 0, stream>>>(uraw, ln2g, ln2b, ubf);
  k_gemm256<2><<<512, 512, 0, stream>>>(ubf, swt, logits, extra, 8192, 4096, 256);

  k_l23<<<16384, 64, 0, stream>>>(qkv, aKb, aQb, l2b, l3a);
  k_attn<<<8192, 256, 0, stream>>>(qkv, logits, l2b, l3a, outh);
  k_c<<<8192, 64, 0, stream>>>(l3a, aVt, outh);
  k_gemm256<3><<<512, 512, 0, stream>>>(outh, Wot, dout, Wo_b, 32768, 1024, 1024);
}

// Round 9
// 727.649 us; speedup vs baseline: 1.0222x; 1.0222x over previous
//
#include <hip/hip_runtime.h>
#include <cstdint>
#include <cstdio>

typedef unsigned short u16;
typedef __attribute__((ext_vector_type(8))) short s8v;
typedef __attribute__((ext_vector_type(4))) float f4v;
typedef __attribute__((ext_vector_type(4))) unsigned short u16x4;
typedef const __attribute__((address_space(1))) void* gas_p;
typedef __attribute__((address_space(3))) void* las_p;

#define DEV __device__ __forceinline__

static constexpr float SCALE_ = 0.125f;             // 1/sqrt(64)
static constexpr float RES_SCALE_ = 0.7071067811865475f;
static constexpr float EPS_ = 1e-5f;

DEV u16 f2bf(float f) {
  uint32_t u = __float_as_uint(f);
  u += 0x7fffu + ((u >> 16) & 1u);
  return (u16)(u >> 16);
}
DEV float bf2f(u16 h) { return __uint_as_float(((uint32_t)h) << 16); }

DEV f4v mfma16(s8v a, s8v b, f4v c) {
  return __builtin_amdgcn_mfma_f32_16x16x32_bf16(a, b, c, 0, 0, 0);
}

#define WAITVM4 asm volatile("s_waitcnt vmcnt(4)" ::: "memory")
#define WAITVM0 asm volatile("s_waitcnt vmcnt(0)" ::: "memory")
#define SCHEDB  __builtin_amdgcn_sched_barrier(0)
#define BAR     __builtin_amdgcn_s_barrier()

// ---------------- utility ----------------

__global__ void k_zero(float* __restrict__ p, long n) {
  long i = (long)blockIdx.x * blockDim.x + threadIdx.x;
  long stride = (long)gridDim.x * blockDim.x;
  for (; i < n; i += stride) p[i] = 0.f;
}

// ---------------- prep mega-kernel helpers ----------------

DEV void dev_cvt(const float* __restrict__ in, u16* __restrict__ out, long n4,
                 int bid, int nblocks) {
  long i = (long)bid * 256 + threadIdx.x;
  long stride = (long)nblocks * 256;
  for (; i < n4; i += stride) {
    f4v v = *(const f4v*)&in[i * 4];
    u16x4 o;
    o.x = f2bf(v.x); o.y = f2bf(v.y); o.z = f2bf(v.z); o.w = f2bf(v.w);
    *(u16x4*)&out[i * 4] = o;
  }
}

// in: (K x N) f32 row-major -> out: (N x K) bf16 row-major. K,N multiples of 64.
DEV void dev_transpose(const float* __restrict__ in, u16* __restrict__ out,
                       int K, int N, int bx, int by, float tile[64][65]) {
  int kb = bx * 64, nb = by * 64;
  for (int i = threadIdx.x; i < 4096; i += 256) {
    int r = i >> 6, c = i & 63;
    tile[r][c] = in[(long)(kb + r) * N + nb + c];
  }
  __syncthreads();
  for (int i = threadIdx.x; i < 4096; i += 256) {
    int c = i >> 6, r = i & 63;
    out[(long)(nb + c) * K + kb + r] = f2bf(tile[r][c]);
  }
}

// aV (H,T,S,dh) f32 -> aVt (H,T,dh,S) bf16, one (h,t) per block
DEV void dev_avt(const float* __restrict__ aV, u16* __restrict__ aVt, int ht,
                 float tile[64][65]) {
  const float* src = aV + (long)ht * 4096;
  for (int i = threadIdx.x; i < 4096; i += 256) {
    int s = i >> 6, d = i & 63;
    tile[s][d] = src[i];
  }
  __syncthreads();
  u16* dst = aVt + (long)ht * 4096;
  for (int i = threadIdx.x; i < 4096; i += 256) {
    int d = i >> 6, s = i & 63;
    dst[i] = f2bf(tile[s][d]);
  }
}

// One kernel for all independent input-preprocessing work (saves ~12 launch gaps).
__launch_bounds__(256)
__global__ void k_prep(const float* __restrict__ x, u16* __restrict__ xbf,
                       const float* __restrict__ Wq, const float* __restrict__ Wk,
                       const float* __restrict__ Wv, const float* __restrict__ Wo,
                       u16* __restrict__ Wqkvt, u16* __restrict__ Wot,
                       const float* __restrict__ ph_w, u16* __restrict__ phwt,
                       const float* __restrict__ shw, u16* __restrict__ swt,
                       const float* __restrict__ pg_w, u16* __restrict__ pgwT,
                       const float* __restrict__ pt_w, u16* __restrict__ ptwT,
                       const float* __restrict__ aK, u16* __restrict__ aKb,
                       const float* __restrict__ aQ, u16* __restrict__ aQb,
                       const float* __restrict__ aV, u16* __restrict__ aVt,
                       const float* __restrict__ sb, float* __restrict__ extra) {
  __shared__ float tile[64][65];
  int b = blockIdx.x;
  if (b < 2048) { dev_cvt(x, xbf, 8388608, b, 2048); return; }
  b -= 2048;
  if (b < 1024) {  // 4x 1024x1024 weight transposes, 256 blocks each
    const float* src = (b < 256) ? Wq : (b < 512) ? Wk : (b < 768) ? Wv : Wo;
    u16* dst = (b < 256) ? Wqkvt : (b < 512) ? (Wqkvt + 1048576)
             : (b < 768) ? (Wqkvt + 2097152) : Wot;
    int id = b & 255;
    dev_transpose(src, dst, 1024, 1024, id & 15, id >> 4, tile);
    return;
  }
  b -= 1024;
  if (b < 256) { dev_transpose(ph_w, phwt, 256, 4096, b & 3, b >> 2, tile); return; }
  b -= 256;
  if (b < 256) { dev_transpose(shw, swt, 256, 4096, b & 3, b >> 2, tile); return; }
  b -= 256;
  if (b < 128) { dev_transpose(pg_w, pgwT, 2048, 256, b & 31, b >> 5, tile); return; }
  b -= 128;
  if (b < 128) {  // pt_w (1024 x 32) -> ptwT (32 x 1024)
    int idx = b * 256 + threadIdx.x;
    int n = idx >> 10, k = idx & 1023;
    ptwT[idx] = f2bf(pt_w[k * 32 + n]);
    return;
  }
  b -= 128;
  if (b < 512) { dev_cvt(aK, aKb, 1048576, b, 512); return; }
  b -= 512;
  if (b < 512) { dev_cvt(aQ, aQb, 1048576, b, 512); return; }
  b -= 512;
  if (b < 1024) { dev_avt(aV, aVt, b, tile); return; }
  b -= 1024;
  {  // extra[h*4096+t*64+s] = sb + SCALE * sum_d aQ*aK   (256 blocks)
    int idx = b * 256 + threadIdx.x;
    const float* q = aQ + (long)idx * 64;
    const float* k = aK + (long)idx * 64;
    float acc = 0.f;
#pragma unroll 8
    for (int d = 0; d < 64; d++) acc += q[d] * k[d];
    extra[idx] = sb[idx] + acc * SCALE_;
  }
}

// ---------------- 256x256 MFMA GEMM (16x16x32), pipelined, 5 barriers/K-tile ----
// C = A(MxK,bf16) * Bt(NxK,bf16)^T.  BK=64, 512 threads = 8 waves (2Mx4N),
// 128 KiB LDS double-buffer, global_load_lds staging with pre-swizzled SOURCE,
// linear LDS dest, swizzled ds_read.  [16x16x32 fragment pattern: measured 0
// LDS bank conflicts; 32x32x16 was 1.9e7 — do not convert.]
// Phase order per K-tile: Q00(Ah0*B01) Q01(Ah0*B23) Q10(Ah1*B01) Q11(Ah1*B23).
// Barrier schedule: pre-MFMA barrier every phase, post-MFMA barrier ONLY in P1
// (publishes b23(t)-read completion before P2's GLOADB overwrite); boundary
// vmcnt(4)+BAR in P3.  Hazard audit in round-2 notes.
// EPI 0: bf16 store. 2: bf16 +aux[(row&15)*4096|col]. 3: f32 (v+aux[col])*RES_SCALE.
template <int EPI>
__launch_bounds__(512)
__global__ void k_gemm256(const u16* __restrict__ A, const u16* __restrict__ Bt,
                          void* __restrict__ Cv, const float* __restrict__ aux,
                          int M, int N, int K) {
  __shared__ u16 lds[65536];  // A: [0,32768) ; B: [32768,65536). half=8192 elems.

  const int nwg = gridDim.x;
  int wg = blockIdx.x;
  if ((nwg & 7) == 0) wg = (wg & 7) * (nwg >> 3) + (wg >> 3);  // XCD swizzle
  const int ntiles = N >> 8;
  const int mt = wg / ntiles, ntb = wg % ntiles;

  const int tid = threadIdx.x;
  const int lane = tid & 63, w = tid >> 6;
  const int wrB = (w >> 2) * 128, wcB = (w & 3) * 64;
  const int lr = lane & 15, lg = lane >> 4;
  const int hA = w >> 2;             // wave's A half (0/1)
  const int hB = (w & 3) >> 1;       // wave's B half
  const int rB0 = (w & 1) * 64;      // wave's B row base within half
  const int xs0 = ((lg) ^ (lr & 7)) << 3;       // frag slot elem offset, ks=0
  const int xs1 = ((4 + lg) ^ (lr & 7)) << 3;   // ks=1
  const int nt = K >> 6;

  const int sr = tid >> 3;
  const int sslot = (tid & 7) ^ (sr & 7);

  // hoisted staging source pointers (per-thread row base + swizzled slot)
  const u16* aSrc = A + (long)(mt * 256 + sr) * K + sslot * 8;
  const u16* bSrc = Bt + (long)(ntb * 256 + sr) * K + sslot * 8;
  const long h128 = (long)128 * K;
  const long r64 = (long)64 * K;

#define GLOADA(tile, h)                                                          \
  do {                                                                           \
    const int bu_ = (tile) & 1;                                                  \
    const long o_ = (long)(tile) * 64 + (h) * h128;                              \
    __builtin_amdgcn_global_load_lds((gas_p)(aSrc + o_), (las_p)&lds[(bu_ * 2 + (h)) * 8192 + w * 512], 16, 0, 0); \
    __builtin_amdgcn_global_load_lds((gas_p)(aSrc + o_ + r64), (las_p)&lds[(bu_ * 2 + (h)) * 8192 + 4096 + w * 512], 16, 0, 0); \
  } while (0)

#define GLOADB(tile, h)                                                          \
  do {                                                                           \
    const int bu_ = (tile) & 1;                                                  \
    const long o_ = (long)(tile) * 64 + (h) * h128;                              \
    __builtin_amdgcn_global_load_lds((gas_p)(bSrc + o_), (las_p)&lds[32768 + (bu_ * 2 + (h)) * 8192 + w * 512], 16, 0, 0); \
    __builtin_amdgcn_global_load_lds((gas_p)(bSrc + o_ + r64), (las_p)&lds[32768 + (bu_ * 2 + (h)) * 8192 + 4096 + w * 512], 16, 0, 0); \
  } while (0)

  f4v acc[8][4];
#pragma unroll
  for (int mi = 0; mi < 8; mi++)
#pragma unroll
    for (int ni = 0; ni < 4; ni++) acc[mi][ni] = (f4v){0.f, 0.f, 0.f, 0.f};

  // ---- prologue: tile0 (A+B) and tile1 (B) staged, drained ----
  GLOADA(0, 0); GLOADA(0, 1);
  GLOADB(0, 0); GLOADB(0, 1);
  {
    const int t1 = (nt > 1) ? 1 : 0;
    GLOADB(t1, 0); GLOADB(t1, 1);
  }
  WAITVM0;
  BAR;

  s8v AF[4][2], b01[2][2], b23[2][2];

  // prologue fragment preload: Ah0(tile0) + B01(tile0), parity 0
  {
    const int aB0 = hA * 8192;
    const int bB0 = 32768 + hB * 8192;
#pragma unroll
    for (int mi = 0; mi < 4; mi++) {
      const int ro = (mi * 16 + lr) * 64;
      AF[mi][0] = *(const s8v*)&lds[aB0 + ro + xs0];
      AF[mi][1] = *(const s8v*)&lds[aB0 + ro + xs1];
    }
#pragma unroll
    for (int ni = 0; ni < 2; ni++) {
      const int ro = (rB0 + ni * 16 + lr) * 64;
      b01[ni][0] = *(const s8v*)&lds[bB0 + ro + xs0];
      b01[ni][1] = *(const s8v*)&lds[bB0 + ro + xs1];
    }
  }
  SCHEDB;

  for (int t = 0; t < nt; ++t) {
    const int p = t & 1, q = p ^ 1;
    const int aN = (t + 1 < nt) ? t + 1 : nt - 1;
    const int bN = (t + 2 < nt) ? t + 2 : nt - 1;
    const int aBase = (p * 2 + hA) * 8192;
    const int bBase = 32768 + (p * 2 + hB) * 8192;
    const int aBaseN = (q * 2 + hA) * 8192;
    const int bBaseN = 32768 + (q * 2 + hB) * 8192;

    // ===== P0: Q00 = Ah0 x B01 ; prefetch b23(t) ; stage A(t+1,h0) =====
#pragma unroll
    for (int ni = 0; ni < 2; ni++) {
      const int ro = (rB0 + (2 + ni) * 16 + lr) * 64;
      b23[ni][0] = *(const s8v*)&lds[bBase + ro + xs0];
      b23[ni][1] = *(const s8v*)&lds[bBase + ro + xs1];
    }
    SCHEDB;
    GLOADA(aN, 0);
    BAR;
    __builtin_amdgcn_s_setprio(1);
#pragma unroll
    for (int mi = 0; mi < 4; mi++)
#pragma unroll
      for (int ks = 0; ks < 2; ks++)
#pragma unroll
        for (int ni = 0; ni < 2; ni++)
          acc[mi][ni] = mfma16(AF[mi][ks], b01[ni][ks], acc[mi][ni]);
    __builtin_amdgcn_s_setprio(0);

    // ===== P1: Q01 = Ah0 x B23 ; interleaved reload AF<-Ah1(t) ; stage A(t+1,h1) =====
    GLOADA(aN, 1);
    BAR;
    __builtin_amdgcn_s_setprio(1);
#pragma unroll
    for (int mi = 0; mi < 4; mi++) {
#pragma unroll
      for (int ks = 0; ks < 2; ks++)
#pragma unroll
        for (int ni = 0; ni < 2; ni++)
          acc[mi][2 + ni] = mfma16(AF[mi][ks], b23[ni][ks], acc[mi][2 + ni]);
      const int ro = (64 + mi * 16 + lr) * 64;
      AF[mi][0] = *(const s8v*)&lds[aBase + ro + xs0];
      AF[mi][1] = *(const s8v*)&lds[aBase + ro + xs1];
      SCHEDB;
    }
    __builtin_amdgcn_s_setprio(0);
    BAR;  // LOAD-BEARING: publishes completion of b23(t) reads (first consumed
          // in this phase) before P2's GLOADB overwrites that region.

    // ===== P2: Q10 = Ah1 x B01 ; stage B(t+2,h0) =====
    GLOADB(bN, 0);
    BAR;
    __builtin_amdgcn_s_setprio(1);
#pragma unroll
    for (int mi = 0; mi < 4; mi++)
#pragma unroll
      for (int ks = 0; ks < 2; ks++)
#pragma unroll
        for (int ni = 0; ni < 2; ni++)
          acc[4 + mi][ni] = mfma16(AF[mi][ks], b01[ni][ks], acc[4 + mi][ni]);
    __builtin_amdgcn_s_setprio(0);

    // ===== P3: Q11 = Ah1 x B23 ; boundary vmcnt(4)+BAR ; prefetch b01(t+1) ;
    //           interleaved reload AF<-Ah0(t+1) ; stage B(t+2,h1) =====
    GLOADB(bN, 1);
    WAITVM4;
    BAR;
#pragma unroll
    for (int ni = 0; ni < 2; ni++) {
      const int ro = (rB0 + ni * 16 + lr) * 64;
      b01[ni][0] = *(const s8v*)&lds[bBaseN + ro + xs0];
      b01[ni][1] = *(const s8v*)&lds[bBaseN + ro + xs1];
    }
    SCHEDB;
    __builtin_amdgcn_s_setprio(1);
#pragma unroll
    for (int mi = 0; mi < 4; mi++) {
#pragma unroll
      for (int ks = 0; ks < 2; ks++)
#pragma unroll
        for (int ni = 0; ni < 2; ni++)
          acc[4 + mi][2 + ni] = mfma16(AF[mi][ks], b23[ni][ks], acc[4 + mi][2 + ni]);
      const int ro = (mi * 16 + lr) * 64;
      AF[mi][0] = *(const s8v*)&lds[aBaseN + ro + xs0];
      AF[mi][1] = *(const s8v*)&lds[aBaseN + ro + xs1];
      SCHEDB;
    }
    __builtin_amdgcn_s_setprio(0);
  }
#undef GLOADA
#undef GLOADB

  // ---- epilogue ----
  const int rbase = mt * 256 + wrB + lg * 4;
  const int cbase = ntb * 256 + wcB + lr;
  if (EPI == 0) {
    u16* C = (u16*)Cv;
#pragma unroll
    for (int mi = 0; mi < 8; mi++)
#pragma unroll
      for (int ni = 0; ni < 4; ni++)
#pragma unroll
        for (int j = 0; j < 4; j++)
          C[(long)(rbase + mi * 16 + j) * N + (cbase + ni * 16)] = f2bf(acc[mi][ni][j]);
  } else if (EPI == 2) {
    u16* C = (u16*)Cv;
#pragma unroll
    for (int mi = 0; mi < 8; mi++)
#pragma unroll
      for (int ni = 0; ni < 4; ni++)
#pragma unroll
        for (int j = 0; j < 4; j++) {
          const int row = rbase + mi * 16 + j;
          const int col = cbase + ni * 16;
          C[(long)row * N + col] = f2bf(acc[mi][ni][j] + aux[((row & 15) << 12) | col]);
        }
  } else {
    float* C = (float*)Cv;
#pragma unroll
    for (int mi = 0; mi < 8; mi++)
#pragma unroll
      for (int ni = 0; ni < 4; ni++)
#pragma unroll
        for (int j = 0; j < 4; j++) {
          const int col = cbase + ni * 16;
          C[(long)(rbase + mi * 16 + j) * N + col] =
              (acc[mi][ni][j] + aux[col]) * RES_SCALE_;
        }
  }
}

// ---------------- generic 128x128 MFMA GEMM (small/medium shapes) ----------------
// EPI 1: f32 +bias[col].
template <int EPI>
__launch_bounds__(256)
__global__ void k_gemm(const u16* __restrict__ A, const u16* __restrict__ Bt,
                       void* __restrict__ Cv, const float* __restrict__ aux,
                       int M, int N, int K) {
  __shared__ u16 As[4096];
  __shared__ u16 Bs[4096];
  const int ntiles = N >> 7;
  const int mt = blockIdx.x / ntiles;
  const int nt = blockIdx.x % ntiles;
  const int tid = threadIdx.x;
  const int lane = tid & 63;
  const int w = tid >> 6;
  const int wr = w >> 1, wc = w & 1;
  const int lr = lane & 15, lg = lane >> 4;

  f4v acc[4][4];
#pragma unroll
  for (int m = 0; m < 4; m++)
#pragma unroll
    for (int n = 0; n < 4; n++) acc[m][n] = (f4v){0.f, 0.f, 0.f, 0.f};

  const u16* aSrc = A + (long)(mt * 128 + (tid >> 2)) * K + ((tid & 3) << 3);
  const u16* bSrc = Bt + (long)(nt * 128 + (tid >> 2)) * K + ((tid & 3) << 3);
  const long rowStep = (long)64 * K;

  const int kIters = K >> 5;
  for (int kb = 0; kb < kIters; kb++) {
    if (kb) __syncthreads();
    const u16* aP = aSrc + (kb << 5);
    const u16* bP = bSrc + (kb << 5);
    __builtin_amdgcn_global_load_lds((gas_p)aP, (las_p)&As[w * 512], 16, 0, 0);
    __builtin_amdgcn_global_load_lds((gas_p)(aP + rowStep), (las_p)&As[2048 + w * 512], 16, 0, 0);
    __builtin_amdgcn_global_load_lds((gas_p)bP, (las_p)&Bs[w * 512], 16, 0, 0);
    __builtin_amdgcn_global_load_lds((gas_p)(bP + rowStep), (las_p)&Bs[2048 + w * 512], 16, 0, 0);
    WAITVM0;
    __syncthreads();

    s8v af[4];
#pragma unroll
    for (int m = 0; m < 4; m++)
      af[m] = *(const s8v*)&As[(wr * 64 + m * 16 + lr) * 32 + (lg << 3)];
#pragma unroll
    for (int n = 0; n < 4; n++) {
      s8v bf = *(const s8v*)&Bs[(wc * 64 + n * 16 + lr) * 32 + (lg << 3)];
#pragma unroll
      for (int m = 0; m < 4; m++) acc[m][n] = mfma16(af[m], bf, acc[m][n]);
    }
  }

  const int rbase = mt * 128 + wr * 64 + lg * 4;
  const int cbase = nt * 128 + wc * 64 + lr;
  {
    float* C = (float*)Cv;
#pragma unroll
    for (int m = 0; m < 4; m++)
#pragma unroll
      for (int n = 0; n < 4; n++)
#pragma unroll
        for (int j = 0; j < 4; j++) {
          int row = rbase + m * 16 + j;
          int col = cbase + n * 16;
          C[(long)row * N + col] = acc[m][n][j] + aux[col];
        }
  }
}

// ---------------- smolgen MFMA layers ----------------

// z(32768x32 bf16) = xbf(32768x1024) @ ptwT(32x1024)^T + ptb
__launch_bounds__(256)
__global__ void k_smola_gemm(const u16* __restrict__ xbf, const u16* __restrict__ ptwT,
                             const float* __restrict__ ptb, u16* __restrict__ z) {
  const int rt = blockIdx.x;
  const int w = threadIdx.x >> 6, lane = threadIdx.x & 63;
  const int lr = lane & 15, lg = lane >> 4;
  const int row0 = rt * 64 + w * 16;
  f4v acc[2];
  acc[0] = (f4v){0.f, 0.f, 0.f, 0.f};
  acc[1] = (f4v){0.f, 0.f, 0.f, 0.f};
  const u16* aBase = xbf + (long)(row0 + lr) * 1024;
  const u16* bBase = ptwT + (long)lr * 1024;
#pragma unroll 4
  for (int k0 = 0; k0 < 1024; k0 += 32) {
    s8v a = *(const s8v*)&aBase[k0 + (lg << 3)];
#pragma unroll
    for (int n = 0; n < 2; n++) {
      s8v b = *(const s8v*)&bBase[(long)(n << 4) * 1024 + k0 + (lg << 3)];
      acc[n] = mfma16(a, b, acc[n]);
    }
  }
#pragma unroll
  for (int n = 0; n < 2; n++)
#pragma unroll
    for (int j = 0; j < 4; j++) {
      int col = (n << 4) + lr;
      z[(long)(row0 + lg * 4 + j) * 32 + col] = f2bf(acc[n][j] + ptb[col]);
    }
}

// uraw2(512x256 f32) = z(512x2048) @ pgwT(256x2048)^T + pgb
// [kept as a separate 128-block kernel: the 32-block fused GEMM+LN variant
//  measured +18.6µs — grid shrink 128->32 starves CUs on a latency-bound loop]
__launch_bounds__(64)
__global__ void k_smolb_gemm(const u16* __restrict__ z, const u16* __restrict__ pgwT,
                             const float* __restrict__ pgb, float* __restrict__ out) {
  const int bid = blockIdx.x;
  const int rt = bid >> 2, ct = bid & 3;
  const int lane = threadIdx.x;
  const int lr = lane & 15, lg = lane >> 4;
  f4v acc[4];
#pragma unroll
  for (int n = 0; n < 4; n++) acc[n] = (f4v){0.f, 0.f, 0.f, 0.f};
  const u16* aBase = z + (long)(rt * 16 + lr) * 2048;
  const u16* bBase = pgwT + (long)(ct * 64 + lr) * 2048;
#pragma unroll 4
  for (int k0 = 0; k0 < 2048; k0 += 32) {
    s8v a = *(const s8v*)&aBase[k0 + (lg << 3)];
#pragma unroll
    for (int n = 0; n < 4; n++) {
      s8v b = *(const s8v*)&bBase[(long)(n << 4) * 2048 + k0 + (lg << 3)];
      acc[n] = mfma16(a, b, acc[n]);
    }
  }
#pragma unroll
  for (int n = 0; n < 4; n++)
#pragma unroll
    for (int j = 0; j < 4; j++) {
      int row = rt * 16 + lg * 4 + j;
      int col = ct * 64 + (n << 4) + lr;
      out[(long)row * 256 + col] = acc[n][j] + pgb[col];
    }
}

// u = LN(silu(in)) per row of 256; in already has bias added. out bf16.
__launch_bounds__(64)
__global__ void k_ln2(const float* __restrict__ uraw, const float* __restrict__ g2,
                      const float* __restrict__ b2, u16* __restrict__ ubf) {
  const int row = blockIdx.x;
  const int lane = threadIdx.x;
  f4v x = *(const f4v*)&uraw[(long)row * 256 + lane * 4];
  float v[4];
  float s = 0.f, q = 0.f;
#pragma unroll
  for (int j = 0; j < 4; j++) {
    float xx = x[j];
    v[j] = xx / (1.f + __expf(-xx));
    s += v[j]; q += v[j] * v[j];
  }
#pragma unroll
  for (int mk = 1; mk < 64; mk <<= 1) { s += __shfl_xor(s, mk); q += __shfl_xor(q, mk); }
  float mean = s * (1.f / 256.f);
  float var = q * (1.f / 256.f) - mean * mean;
  float rs = rsqrtf(var + EPS_);
  u16x4 o;
  float o0 = (v[0] - mean) * rs * g2[lane * 4 + 0] + b2[lane * 4 + 0];
  float o1 = (v[1] - mean) * rs * g2[lane * 4 + 1] + b2[lane * 4 + 1];
  float o2 = (v[2] - mean) * rs * g2[lane * 4 + 2] + b2[lane * 4 + 2];
  float o3 = (v[3] - mean) * rs * g2[lane * 4 + 3] + b2[lane * 4 + 3];
  o.x = f2bf(o0); o.y = f2bf(o1); o.z = f2bf(o2); o.w = f2bf(o3);
  *(u16x4*)&ubf[(long)row * 256 + lane * 4] = o;
}

// ---------------- batched 64x64x64 MFMA kernels ----------------

// merged l2 + l3 (independent, same shape) — saves one launch gap.
__launch_bounds__(64)
__global__ void k_l23(const u16* __restrict__ qkv, const u16* __restrict__ aKb,
                      const u16* __restrict__ aQb, u16* __restrict__ l2b,
                      u16* __restrict__ l3a) {
  const int lane = threadIdx.x;
  const int lr = lane & 15, lg = lane >> 4;
  f4v acc[4][4];
#pragma unroll
  for (int m = 0; m < 4; m++)
#pragma unroll
    for (int n = 0; n < 4; n++) acc[m][n] = (f4v){0.f, 0.f, 0.f, 0.f};

  if (blockIdx.x < 8192) {
    const int bid = blockIdx.x;
    const int bt = bid & 7, t = (bid >> 3) & 63, h = bid >> 9;
    const u16* qb = qkv + (long)t * 3072 + h * 64;
    const u16* kb = aKb + ((long)h * 64 + t) * 4096;
#pragma unroll
    for (int ks = 0; ks < 2; ks++) {
      s8v a[4], bb[4];
#pragma unroll
      for (int m = 0; m < 4; m++) {
        int brow = bt * 64 + m * 16 + lr;
        a[m] = *(const s8v*)&qb[(long)brow * 196608 + ks * 32 + (lg << 3)];
      }
#pragma unroll
      for (int n = 0; n < 4; n++)
        bb[n] = *(const s8v*)&kb[(n * 16 + lr) * 64 + ks * 32 + (lg << 3)];
#pragma unroll
      for (int m = 0; m < 4; m++)
#pragma unroll
        for (int n = 0; n < 4; n++) acc[m][n] = mfma16(a[m], bb[n], acc[m][n]);
    }
    u16* dst = l2b + ((long)h * 64 + t) * 32768;  // + b*64 + s
#pragma unroll
    for (int m = 0; m < 4; m++)
#pragma unroll
      for (int n = 0; n < 4; n++)
#pragma unroll
        for (int j = 0; j < 4; j++) {
          int brow = bt * 64 + m * 16 + lg * 4 + j;
          int s = n * 16 + lr;
          dst[(long)brow * 64 + s] = f2bf(SCALE_ * acc[m][n][j]);
        }
  } else {
    const int bid = blockIdx.x - 8192;
    const int bt = bid & 7, s = (bid >> 3) & 63, h = bid >> 9;
    const u16* kb = qkv + (long)s * 3072 + 1024 + h * 64;
    const u16* qb = aQb + (long)h * 262144 + (long)s * 64;
#pragma unroll
    for (int ks = 0; ks < 2; ks++) {
      s8v a[4], bb[4];
#pragma unroll
      for (int m = 0; m < 4; m++) {
        int brow = bt * 64 + m * 16 + lr;
        a[m] = *(const s8v*)&kb[(long)brow * 196608 + ks * 32 + (lg << 3)];
      }
#pragma unroll
      for (int n = 0; n < 4; n++) {
        int tc = n * 16 + lr;
        bb[n] = *(const s8v*)&qb[(long)tc * 4096 + ks * 32 + (lg << 3)];
      }
#pragma unroll
      for (int m = 0; m < 4; m++)
#pragma unroll
        for (int n = 0; n < 4; n++) acc[m][n] = mfma16(a[m], bb[n], acc[m][n]);
    }
#pragma unroll
    for (int m = 0; m < 4; m++)
#pragma unroll
      for (int n = 0; n < 4; n++)
#pragma unroll
        for (int j = 0; j < 4; j++) {
          int brow = bt * 64 + m * 16 + lg * 4 + j;
          int tc = n * 16 + lr;
          long idx = (((long)brow * 16 + h) * 64 + s) * 64 + tc;
          l3a[idx] = f2bf(SCALE_ * acc[m][n][j]);
        }
  }
}

// out_heads[b,t,h,d] += sum_s attn[b,h,t,s]*aV[h,t,s,d];  grid h*512 + t*8 + bt
__launch_bounds__(64)
__global__ void k_c(const u16* __restrict__ attnb, const u16* __restrict__ aVt,
                    u16* __restrict__ outh) {
  const int bid = blockIdx.x;
  const int bt = bid & 7, t = (bid >> 3) & 63, h = bid >> 9;
  const int lane = threadIdx.x;
  const int lr = lane & 15, lg = lane >> 4;
  f4v acc[4][4];
#pragma unroll
  for (int m = 0; m < 4; m++)
#pragma unroll
    for (int n = 0; n < 4; n++) acc[m][n] = (f4v){0.f, 0.f, 0.f, 0.f};
  const u16* ab = attnb + ((long)h * 64 + t) * 64;      // + b*65536
  const u16* vb = aVt + ((long)h * 64 + t) * 4096;      // rows d, contiguous s
#pragma unroll
  for (int ks = 0; ks < 2; ks++) {
    s8v a[4], bb[4];
#pragma unroll
    for (int m = 0; m < 4; m++) {
      int brow = bt * 64 + m * 16 + lr;
      a[m] = *(const s8v*)&ab[(long)brow * 65536 + ks * 32 + (lg << 3)];
    }
#pragma unroll
    for (int n = 0; n < 4; n++)
      bb[n] = *(const s8v*)&vb[(n * 16 + lr) * 64 + ks * 32 + (lg << 3)];
#pragma unroll
    for (int m = 0; m < 4; m++)
#pragma unroll
      for (int n = 0; n < 4; n++) acc[m][n] = mfma16(a[m], bb[n], acc[m][n]);
  }
#pragma unroll
  for (int m = 0; m < 4; m++)
#pragma unroll
    for (int n = 0; n < 4; n++)
#pragma unroll
      for (int j = 0; j < 4; j++) {
        int brow = bt * 64 + m * 16 + lg * 4 + j;
        int d = n * 16 + lr;
        long idx = ((long)brow * 64 + t) * 1024 + h * 64 + d;
        outh[idx] = f2bf(bf2f(outh[idx]) + acc[m][n][j]);
      }
}

// ---------------- attention core: per (b,h) ----------------
// l3a slice staged COALESCED into Ps during the initial staging loop; the
// transposed [s][t] p-compute read comes from LDS (4x transaction amplification
// removed).  Pad 72 => 144B rows = 9x16B so staged s8v writes stay 16B-aligned;
// transposed u16x4 reads are 2-way bank-aliased (free).  Barrier count
// unchanged (first sync covers staging; pre-P-write sync protects Ps overwrite).
__launch_bounds__(256)
__global__ void k_attn(const u16* __restrict__ qkv, const u16* __restrict__ logits,
                       const u16* __restrict__ l2b, u16* __restrict__ l3a,
                       u16* __restrict__ outh) {
  __shared__ u16 Qs[64 * 72];
  __shared__ u16 Ks[64 * 72];
  __shared__ u16 Vt[64 * 72];
  __shared__ u16 Ps[64 * 72];   // staged l3a slice first, then P
  const int bh = blockIdx.x;
  const int b = bh >> 4, h = bh & 15;
  const int tid = threadIdx.x;
  const int lane = tid & 63, w = tid >> 6;
  const int lr = lane & 15, lg = lane >> 4;
  const u16* qbase = qkv + (long)b * 196608 + h * 64;
  const long base = (long)bh * 4096;

#pragma unroll
  for (int c = 0; c < 2; c++) {
    int flat = c * 2048 + tid * 8;
    int row = flat >> 6, k = flat & 63;
    const u16* src = &qbase[(long)row * 3072 + k];
    *(s8v*)&Qs[row * 72 + k] = *(const s8v*)(src);
    *(s8v*)&Ks[row * 72 + k] = *(const s8v*)(src + 1024);
    s8v v = *(const s8v*)(src + 2048);
#pragma unroll
    for (int j = 0; j < 8; j++) Vt[(k + j) * 72 + row] = (u16)v[j];
    // coalesced l3a staging: Ps[s][t] mirrors global [s-major] layout
    *(s8v*)&Ps[row * 72 + k] = *(const s8v*)&l3a[base + flat];
  }
  __syncthreads();

  f4v sacc[4];
#pragma unroll
  for (int n = 0; n < 4; n++) sacc[n] = (f4v){0.f, 0.f, 0.f, 0.f};
#pragma unroll
  for (int ks = 0; ks < 2; ks++) {
    s8v a = *(const s8v*)&Qs[(w * 16 + lr) * 72 + ks * 32 + (lg << 3)];
#pragma unroll
    for (int n = 0; n < 4; n++) {
      s8v bb = *(const s8v*)&Ks[(n * 16 + lr) * 72 + ks * 32 + (lg << 3)];
      sacc[n] = mfma16(a, bb, sacc[n]);
    }
  }

  const int r0 = w * 16 + lg * 4;
  float p[4][4];
#pragma unroll
  for (int n = 0; n < 4; n++) {
    int s = n * 16 + lr;
    u16x4 l3v = *(const u16x4*)&Ps[s * 72 + r0];   // LDS (staged l3a)
#pragma unroll
    for (int j = 0; j < 4; j++) {
      float l3f = bf2f(((const u16*)&l3v)[j]);
      float l2f = bf2f(l2b[(((long)h * 64 + r0 + j) * 512 + b) * 64 + s]);
      float lgf = bf2f(logits[base + (r0 + j) * 64 + s]);
      p[n][j] = sacc[n][j] * SCALE_ + lgf + l3f + l2f;
    }
  }
#pragma unroll
  for (int j = 0; j < 4; j++) {
    float m = fmaxf(fmaxf(p[0][j], p[1][j]), fmaxf(p[2][j], p[3][j]));
    m = fmaxf(m, __shfl_xor(m, 1));
    m = fmaxf(m, __shfl_xor(m, 2));
    m = fmaxf(m, __shfl_xor(m, 4));
    m = fmaxf(m, __shfl_xor(m, 8));
    float s0 = 0.f;
#pragma unroll
    for (int n = 0; n < 4; n++) { p[n][j] = __expf(p[n][j] - m); s0 += p[n][j]; }
    s0 += __shfl_xor(s0, 1);
    s0 += __shfl_xor(s0, 2);
    s0 += __shfl_xor(s0, 4);
    s0 += __shfl_xor(s0, 8);
    float inv = 1.f / s0;
#pragma unroll
    for (int n = 0; n < 4; n++) p[n][j] *= inv;
  }

  // All Ps-as-l3a reads complete in every thread past this barrier; safe to
  // overwrite Ps with P (and l3a global with P for k_c).
  __syncthreads();

#pragma unroll
  for (int n = 0; n < 4; n++) {
    int s = n * 16 + lr;
#pragma unroll
    for (int j = 0; j < 4; j++) {
      u16 pb = f2bf(p[n][j]);
      l3a[base + (r0 + j) * 64 + s] = pb;
      Ps[(r0 + j) * 72 + s] = pb;
    }
  }
  __syncthreads();

  f4v oacc[4];
#pragma unroll
  for (int n = 0; n < 4; n++) oacc[n] = (f4v){0.f, 0.f, 0.f, 0.f};
#pragma unroll
  for (int ks = 0; ks < 2; ks++) {
    s8v a = *(const s8v*)&Ps[(w * 16 + lr) * 72 + ks * 32 + (lg << 3)];
#pragma unroll
    for (int n = 0; n < 4; n++) {
      s8v vb = *(const s8v*)&Vt[(n * 16 + lr) * 72 + ks * 32 + (lg << 3)];
      oacc[n] = mfma16(a, vb, oacc[n]);
    }
  }
  u16* obase = outh + (long)b * 65536 + h * 64;
#pragma unroll
  for (int n = 0; n < 4; n++)
#pragma unroll
    for (int j = 0; j < 4; j++)
      obase[(long)(r0 + j) * 1024 + n * 16 + lr] = f2bf(oacc[n][j]);
}

// ---------------- launcher ----------------

extern "C" void kernel_launch(void* const* d_in, const int* in_sizes, int n_in,
                              void* d_out, int out_size, void* d_ws, size_t ws_size,
                              hipStream_t stream) {
  (void)in_sizes; (void)n_in;
  const float* x    = (const float*)d_in[0];
  const float* Wq   = (const float*)d_in[1];
  const float* Wk   = (const float*)d_in[2];
  const float* Wv   = (const float*)d_in[3];
  const float* Wo_w = (const float*)d_in[4];
  const float* Wo_b = (const float*)d_in[5];
  const float* sb   = (const float*)d_in[6];
  const float* aQ   = (const float*)d_in[7];
  const float* aK   = (const float*)d_in[8];
  const float* aV   = (const float*)d_in[9];
  const float* pt_w = (const float*)d_in[10];
  const float* pt_b = (const float*)d_in[11];
  const float* pg_w = (const float*)d_in[12];
  const float* pg_b = (const float*)d_in[13];
  const float* ph_w = (const float*)d_in[14];
  const float* ph_b = (const float*)d_in[15];
  const float* ln1g = (const float*)d_in[16];
  const float* ln1b = (const float*)d_in[17];
  const float* ln2g = (const float*)d_in[18];
  const float* ln2b = (const float*)d_in[19];
  const float* shw  = (const float*)d_in[20];

  char* wsp = (char*)d_ws;
  size_t off = 0;
  auto alloc = [&](size_t bytes) {
    void* p = wsp + off;
    off += (bytes + 255) & ~(size_t)255;
    return p;
  };
  u16*   xbf    = (u16*)alloc(33554432ull * 2);    // also reused as outh
  u16*   qkv    = (u16*)alloc(100663296ull * 2);   // 32768 x 3072
  u16*   logits = (u16*)alloc(33554432ull * 2);    // (B,H,T,S) bf16 (smolgen+extra)
  u16*   l3a    = (u16*)alloc(33554432ull * 2);    // l3 term, then attn probs
  u16*   l2b    = (u16*)alloc(33554432ull * 2);    // l2 term (h,t,b,s)
  u16*   Wqkvt  = (u16*)alloc(3145728ull * 2);     // 3072 x 1024
  u16*   Wot    = (u16*)alloc(1048576ull * 2);
  u16*   phwt   = (u16*)alloc(1048576ull * 2);     // 4096 x 256
  u16*   swt    = (u16*)alloc(1048576ull * 2);     // 4096 x 256
  u16*   aKb    = (u16*)alloc(4194304ull * 2);
  u16*   aQb    = (u16*)alloc(4194304ull * 2);
  u16*   aVt    = (u16*)alloc(4194304ull * 2);
  float* extra  = (float*)alloc(65536ull * 4);
  u16*   z      = (u16*)alloc(1048576ull * 2);     // 32768 x 32
  u16*   g      = (u16*)alloc(131072ull * 2);      // 512 x 256
  float* uraw   = (float*)alloc(2097152ull * 4);   // 512 x 4096
  u16*   ubf    = (u16*)alloc(2097152ull * 2);     // 8192 x 256
  u16*   ptwT   = (u16*)alloc(32768ull * 2);       // 32 x 1024
  u16*   pgwT   = (u16*)alloc(524288ull * 2);      // 256 x 2048
  float* uraw2  = (float*)alloc(131072ull * 4);    // 512 x 256
  u16*   outh   = xbf;                             // alias: xbf dead after smolgen A
  float* dout   = (float*)d_out;

  if (off > ws_size) {
    fprintf(stderr, "[kernel_launch] insufficient workspace: need %zu have %zu\n",
            off, ws_size);
    k_zero<<<2048, 256, 0, stream>>>(dout, (long)out_size);
    return;
  }

  // all independent input prep in one launch
  k_prep<<<6144, 256, 0, stream>>>(x, xbf, Wq, Wk, Wv, Wo_w, Wqkvt, Wot,
                                   ph_w, phwt, shw, swt, pg_w, pgwT, pt_w, ptwT,
                                   aK, aKb, aQ, aQb, aV, aVt, sb, extra);

  k_gemm256<0><<<1536, 512, 0, stream>>>(xbf, Wqkvt, qkv, nullptr, 32768, 3072, 1024);

  k_smola_gemm<<<512, 256, 0, stream>>>(xbf, ptwT, pt_b, z);
  k_smolb_gemm<<<128, 64, 0, stream>>>(z, pgwT, pg_b, uraw2);
  k_ln2<<<512, 64, 0, stream>>>(uraw2, ln1g, ln1b, g);
  k_gemm<1><<<128, 256, 0, stream>>>(g, phwt, uraw, ph_b, 512, 4096, 256);
  k_ln2<<<8192, 64, 0, stream>>>(uraw, ln2g, ln2b, ubf);
  k_gemm256<2><<<512, 512, 0, stream>>>(ubf, swt, logits, extra, 8192, 4096, 256);

  k_l23<<<16384, 64, 0, stream>>>(qkv, aKb, aQb, l2b, l3a);
  k_attn<<<8192, 256, 0, stream>>>(qkv, logits, l2b, l3a, outh);
  k_c<<<8192, 64, 0, stream>>>(l3a, aVt, outh);
  k_gemm256<3><<<512, 512, 0, stream>>>(outh, Wot, dout, Wo_b, 32768, 1024, 1024);
}

// Round 10
// 720.989 us; speedup vs baseline: 1.0316x; 1.0092x over previous
//
#include <hip/hip_runtime.h>
#include <cstdint>
#include <cstdio>

typedef unsigned short u16;
typedef __attribute__((ext_vector_type(8))) short s8v;
typedef __attribute__((ext_vector_type(4))) float f4v;
typedef __attribute__((ext_vector_type(4))) unsigned short u16x4;
typedef const __attribute__((address_space(1))) void* gas_p;
typedef __attribute__((address_space(3))) void* las_p;

#define DEV __device__ __forceinline__

static constexpr float SCALE_ = 0.125f;             // 1/sqrt(64)
static constexpr float RES_SCALE_ = 0.7071067811865475f;
static constexpr float EPS_ = 1e-5f;

DEV u16 f2bf(float f) {
  uint32_t u = __float_as_uint(f);
  u += 0x7fffu + ((u >> 16) & 1u);
  return (u16)(u >> 16);
}
DEV float bf2f(u16 h) { return __uint_as_float(((uint32_t)h) << 16); }

DEV f4v mfma16(s8v a, s8v b, f4v c) {
  return __builtin_amdgcn_mfma_f32_16x16x32_bf16(a, b, c, 0, 0, 0);
}

#define WAITVM4 asm volatile("s_waitcnt vmcnt(4)" ::: "memory")
#define WAITVM0 asm volatile("s_waitcnt vmcnt(0)" ::: "memory")
#define SCHEDB  __builtin_amdgcn_sched_barrier(0)
#define BAR     __builtin_amdgcn_s_barrier()

// ---------------- utility ----------------

__global__ void k_zero(float* __restrict__ p, long n) {
  long i = (long)blockIdx.x * blockDim.x + threadIdx.x;
  long stride = (long)gridDim.x * blockDim.x;
  for (; i < n; i += stride) p[i] = 0.f;
}

// ---------------- prep mega-kernel helpers ----------------

DEV void dev_cvt(const float* __restrict__ in, u16* __restrict__ out, long n4,
                 int bid, int nblocks) {
  long i = (long)bid * 256 + threadIdx.x;
  long stride = (long)nblocks * 256;
  for (; i < n4; i += stride) {
    f4v v = *(const f4v*)&in[i * 4];
    u16x4 o;
    o.x = f2bf(v.x); o.y = f2bf(v.y); o.z = f2bf(v.z); o.w = f2bf(v.w);
    *(u16x4*)&out[i * 4] = o;
  }
}

// in: (K x N) f32 row-major -> out: (N x K) bf16 row-major. K,N multiples of 64.
DEV void dev_transpose(const float* __restrict__ in, u16* __restrict__ out,
                       int K, int N, int bx, int by, float tile[64][65]) {
  int kb = bx * 64, nb = by * 64;
  for (int i = threadIdx.x; i < 4096; i += 256) {
    int r = i >> 6, c = i & 63;
    tile[r][c] = in[(long)(kb + r) * N + nb + c];
  }
  __syncthreads();
  for (int i = threadIdx.x; i < 4096; i += 256) {
    int c = i >> 6, r = i & 63;
    out[(long)(nb + c) * K + kb + r] = f2bf(tile[r][c]);
  }
}

// aV (H,T,S,dh) f32 -> aVt (H,T,dh,S) bf16, one (h,t) per block
DEV void dev_avt(const float* __restrict__ aV, u16* __restrict__ aVt, int ht,
                 float tile[64][65]) {
  const float* src = aV + (long)ht * 4096;
  for (int i = threadIdx.x; i < 4096; i += 256) {
    int s = i >> 6, d = i & 63;
    tile[s][d] = src[i];
  }
  __syncthreads();
  u16* dst = aVt + (long)ht * 4096;
  for (int i = threadIdx.x; i < 4096; i += 256) {
    int d = i >> 6, s = i & 63;
    dst[i] = f2bf(tile[s][d]);
  }
}

// One kernel for all independent input-preprocessing work (saves ~12 launch gaps).
__launch_bounds__(256)
__global__ void k_prep(const float* __restrict__ x, u16* __restrict__ xbf,
                       const float* __restrict__ Wq, const float* __restrict__ Wk,
                       const float* __restrict__ Wv, const float* __restrict__ Wo,
                       u16* __restrict__ Wqkvt, u16* __restrict__ Wot,
                       const float* __restrict__ ph_w, u16* __restrict__ phwt,
                       const float* __restrict__ shw, u16* __restrict__ swt,
                       const float* __restrict__ pg_w, u16* __restrict__ pgwT,
                       const float* __restrict__ pt_w, u16* __restrict__ ptwT,
                       const float* __restrict__ aK, u16* __restrict__ aKb,
                       const float* __restrict__ aQ, u16* __restrict__ aQb,
                       const float* __restrict__ aV, u16* __restrict__ aVt,
                       const float* __restrict__ sb, float* __restrict__ extra) {
  __shared__ float tile[64][65];
  int b = blockIdx.x;
  if (b < 2048) { dev_cvt(x, xbf, 8388608, b, 2048); return; }
  b -= 2048;
  if (b < 1024) {  // 4x 1024x1024 weight transposes, 256 blocks each
    const float* src = (b < 256) ? Wq : (b < 512) ? Wk : (b < 768) ? Wv : Wo;
    u16* dst = (b < 256) ? Wqkvt : (b < 512) ? (Wqkvt + 1048576)
             : (b < 768) ? (Wqkvt + 2097152) : Wot;
    int id = b & 255;
    dev_transpose(src, dst, 1024, 1024, id & 15, id >> 4, tile);
    return;
  }
  b -= 1024;
  if (b < 256) { dev_transpose(ph_w, phwt, 256, 4096, b & 3, b >> 2, tile); return; }
  b -= 256;
  if (b < 256) { dev_transpose(shw, swt, 256, 4096, b & 3, b >> 2, tile); return; }
  b -= 256;
  if (b < 128) { dev_transpose(pg_w, pgwT, 2048, 256, b & 31, b >> 5, tile); return; }
  b -= 128;
  if (b < 128) {  // pt_w (1024 x 32) -> ptwT (32 x 1024)
    int idx = b * 256 + threadIdx.x;
    int n = idx >> 10, k = idx & 1023;
    ptwT[idx] = f2bf(pt_w[k * 32 + n]);
    return;
  }
  b -= 128;
  if (b < 512) { dev_cvt(aK, aKb, 1048576, b, 512); return; }
  b -= 512;
  if (b < 512) { dev_cvt(aQ, aQb, 1048576, b, 512); return; }
  b -= 512;
  if (b < 1024) { dev_avt(aV, aVt, b, tile); return; }
  b -= 1024;
  {  // extra[h*4096+t*64+s] = sb + SCALE * sum_d aQ*aK   (256 blocks)
    int idx = b * 256 + threadIdx.x;
    const float* q = aQ + (long)idx * 64;
    const float* k = aK + (long)idx * 64;
    float acc = 0.f;
#pragma unroll 8
    for (int d = 0; d < 64; d++) acc += q[d] * k[d];
    extra[idx] = sb[idx] + acc * SCALE_;
  }
}

// ---------------- 256x256 MFMA GEMM (16x16x32), pipelined, 2 barriers/K-tile ----
// C = A(MxK,bf16) * Bt(NxK,bf16)^T.  BK=64, 512 threads = 8 waves (2Mx4N),
// 128 KiB LDS double-buffer, global_load_lds staging with pre-swizzled SOURCE,
// linear LDS dest, swizzled ds_read.  [16x16x32 fragment pattern: measured 0
// LDS bank conflicts; 32x32x16 was 1.9e7 — do not convert.]
// Phase order per K-tile: Q00(Ah0*B01) Q01(Ah0*B23) Q10(Ah1*B01) Q11(Ah1*B23).
// Barrier schedule (R9 thinning, full hazard audit): ONLY two barriers/K-tile —
//  (1) post-P1 BAR: publishes completion of b23(t) register-reads before
//      P2/P3's GLOADB(t+2,·) overwrite B(t,·);
//  (2) P3's vmcnt(4)+BAR: completes+publishes A(t+1)+B(t+1) in LDS (12
//      outstanding at the wait; oldest 8 = A(t+1,h0/h1)+B(t+1,h0/h1)) before
//      the P3 b01(t+1)/AF(t+1) reads and the next tile's b23 reads.
// Removed pre-MFMA barriers P0/P1/P2: GLOADA(t+1,·) clobbers stale A(t-1,·)
// whose last readers (P1(t-1) AF reloads) finished before P3(t-1)'s barrier;
// per-wave ds_read->MFMA readiness is compiler lgkmcnt; GLOAD issue points
// pinned with sched_barrier(0).
// EPI 0: bf16 store. 2: bf16 +aux[(row&15)*4096|col]. 3: f32 (v+aux[col])*RES_SCALE.
template <int EPI>
__launch_bounds__(512)
__global__ void k_gemm256(const u16* __restrict__ A, const u16* __restrict__ Bt,
                          void* __restrict__ Cv, const float* __restrict__ aux,
                          int M, int N, int K) {
  __shared__ u16 lds[65536];  // A: [0,32768) ; B: [32768,65536). half=8192 elems.

  const int nwg = gridDim.x;
  int wg = blockIdx.x;
  if ((nwg & 7) == 0) wg = (wg & 7) * (nwg >> 3) + (wg >> 3);  // XCD swizzle
  const int ntiles = N >> 8;
  const int mt = wg / ntiles, ntb = wg % ntiles;

  const int tid = threadIdx.x;
  const int lane = tid & 63, w = tid >> 6;
  const int wrB = (w >> 2) * 128, wcB = (w & 3) * 64;
  const int lr = lane & 15, lg = lane >> 4;
  const int hA = w >> 2;             // wave's A half (0/1)
  const int hB = (w & 3) >> 1;       // wave's B half
  const int rB0 = (w & 1) * 64;      // wave's B row base within half
  const int xs0 = ((lg) ^ (lr & 7)) << 3;       // frag slot elem offset, ks=0
  const int xs1 = ((4 + lg) ^ (lr & 7)) << 3;   // ks=1
  const int nt = K >> 6;

  const int sr = tid >> 3;
  const int sslot = (tid & 7) ^ (sr & 7);

  // hoisted staging source pointers (per-thread row base + swizzled slot)
  const u16* aSrc = A + (long)(mt * 256 + sr) * K + sslot * 8;
  const u16* bSrc = Bt + (long)(ntb * 256 + sr) * K + sslot * 8;
  const long h128 = (long)128 * K;
  const long r64 = (long)64 * K;

#define GLOADA(tile, h)                                                          \
  do {                                                                           \
    const int bu_ = (tile) & 1;                                                  \
    const long o_ = (long)(tile) * 64 + (h) * h128;                              \
    __builtin_amdgcn_global_load_lds((gas_p)(aSrc + o_), (las_p)&lds[(bu_ * 2 + (h)) * 8192 + w * 512], 16, 0, 0); \
    __builtin_amdgcn_global_load_lds((gas_p)(aSrc + o_ + r64), (las_p)&lds[(bu_ * 2 + (h)) * 8192 + 4096 + w * 512], 16, 0, 0); \
  } while (0)

#define GLOADB(tile, h)                                                          \
  do {                                                                           \
    const int bu_ = (tile) & 1;                                                  \
    const long o_ = (long)(tile) * 64 + (h) * h128;                              \
    __builtin_amdgcn_global_load_lds((gas_p)(bSrc + o_), (las_p)&lds[32768 + (bu_ * 2 + (h)) * 8192 + w * 512], 16, 0, 0); \
    __builtin_amdgcn_global_load_lds((gas_p)(bSrc + o_ + r64), (las_p)&lds[32768 + (bu_ * 2 + (h)) * 8192 + 4096 + w * 512], 16, 0, 0); \
  } while (0)

  f4v acc[8][4];
#pragma unroll
  for (int mi = 0; mi < 8; mi++)
#pragma unroll
    for (int ni = 0; ni < 4; ni++) acc[mi][ni] = (f4v){0.f, 0.f, 0.f, 0.f};

  // ---- prologue: tile0 (A+B) and tile1 (B) staged, drained ----
  GLOADA(0, 0); GLOADA(0, 1);
  GLOADB(0, 0); GLOADB(0, 1);
  {
    const int t1 = (nt > 1) ? 1 : 0;
    GLOADB(t1, 0); GLOADB(t1, 1);
  }
  WAITVM0;
  BAR;

  s8v AF[4][2], b01[2][2], b23[2][2];

  // prologue fragment preload: Ah0(tile0) + B01(tile0), parity 0
  {
    const int aB0 = hA * 8192;
    const int bB0 = 32768 + hB * 8192;
#pragma unroll
    for (int mi = 0; mi < 4; mi++) {
      const int ro = (mi * 16 + lr) * 64;
      AF[mi][0] = *(const s8v*)&lds[aB0 + ro + xs0];
      AF[mi][1] = *(const s8v*)&lds[aB0 + ro + xs1];
    }
#pragma unroll
    for (int ni = 0; ni < 2; ni++) {
      const int ro = (rB0 + ni * 16 + lr) * 64;
      b01[ni][0] = *(const s8v*)&lds[bB0 + ro + xs0];
      b01[ni][1] = *(const s8v*)&lds[bB0 + ro + xs1];
    }
  }
  SCHEDB;

  for (int t = 0; t < nt; ++t) {
    const int p = t & 1, q = p ^ 1;
    const int aN = (t + 1 < nt) ? t + 1 : nt - 1;
    const int bN = (t + 2 < nt) ? t + 2 : nt - 1;
    const int aBase = (p * 2 + hA) * 8192;
    const int bBase = 32768 + (p * 2 + hB) * 8192;
    const int aBaseN = (q * 2 + hA) * 8192;
    const int bBaseN = 32768 + (q * 2 + hB) * 8192;

    // ===== P0: Q00 = Ah0 x B01 ; prefetch b23(t) ; stage A(t+1,h0) =====
    // (pre-MFMA barrier removed: GLOADA(t+1,h0) clobbers stale A(t-1,h0),
    //  readers done before P3(t-1) BAR; b23(t) published by P3(t-1) vmcnt+BAR)
#pragma unroll
    for (int ni = 0; ni < 2; ni++) {
      const int ro = (rB0 + (2 + ni) * 16 + lr) * 64;
      b23[ni][0] = *(const s8v*)&lds[bBase + ro + xs0];
      b23[ni][1] = *(const s8v*)&lds[bBase + ro + xs1];
    }
    SCHEDB;
    GLOADA(aN, 0);
    SCHEDB;
    __builtin_amdgcn_s_setprio(1);
#pragma unroll
    for (int mi = 0; mi < 4; mi++)
#pragma unroll
      for (int ks = 0; ks < 2; ks++)
#pragma unroll
        for (int ni = 0; ni < 2; ni++)
          acc[mi][ni] = mfma16(AF[mi][ks], b01[ni][ks], acc[mi][ni]);
    __builtin_amdgcn_s_setprio(0);

    // ===== P1: Q01 = Ah0 x B23 ; interleaved reload AF<-Ah1(t) ; stage A(t+1,h1) =====
    // (pre-MFMA barrier removed: GLOADA(t+1,h1) clobbers stale A(t-1,h1))
    GLOADA(aN, 1);
    SCHEDB;
    __builtin_amdgcn_s_setprio(1);
#pragma unroll
    for (int mi = 0; mi < 4; mi++) {
#pragma unroll
      for (int ks = 0; ks < 2; ks++)
#pragma unroll
        for (int ni = 0; ni < 2; ni++)
          acc[mi][2 + ni] = mfma16(AF[mi][ks], b23[ni][ks], acc[mi][2 + ni]);
      const int ro = (64 + mi * 16 + lr) * 64;
      AF[mi][0] = *(const s8v*)&lds[aBase + ro + xs0];
      AF[mi][1] = *(const s8v*)&lds[aBase + ro + xs1];
      SCHEDB;
    }
    __builtin_amdgcn_s_setprio(0);
    BAR;  // LOAD-BEARING #1: publishes completion of b23(t) reads (consumed by
          // the MFMAs above) before P2/P3's GLOADB(t+2,·) overwrites B(t,·).

    // ===== P2: Q10 = Ah1 x B01 ; stage B(t+2,h0) =====
    // (pre-MFMA barrier removed: GLOADB guarded by the post-P1 BAR above)
    GLOADB(bN, 0);
    SCHEDB;
    __builtin_amdgcn_s_setprio(1);
#pragma unroll
    for (int mi = 0; mi < 4; mi++)
#pragma unroll
      for (int ks = 0; ks < 2; ks++)
#pragma unroll
        for (int ni = 0; ni < 2; ni++)
          acc[4 + mi][ni] = mfma16(AF[mi][ks], b01[ni][ks], acc[4 + mi][ni]);
    __builtin_amdgcn_s_setprio(0);

    // ===== P3: Q11 = Ah1 x B23 ; boundary vmcnt(4)+BAR ; prefetch b01(t+1) ;
    //           interleaved reload AF<-Ah0(t+1) ; stage B(t+2,h1) =====
    GLOADB(bN, 1);
    WAITVM4;
    BAR;  // LOAD-BEARING #2: A(t+1)+B(t+1) complete in LDS and published.
#pragma unroll
    for (int ni = 0; ni < 2; ni++) {
      const int ro = (rB0 + ni * 16 + lr) * 64;
      b01[ni][0] = *(const s8v*)&lds[bBaseN + ro + xs0];
      b01[ni][1] = *(const s8v*)&lds[bBaseN + ro + xs1];
    }
    SCHEDB;
    __builtin_amdgcn_s_setprio(1);
#pragma unroll
    for (int mi = 0; mi < 4; mi++) {
#pragma unroll
      for (int ks = 0; ks < 2; ks++)
#pragma unroll
        for (int ni = 0; ni < 2; ni++)
          acc[4 + mi][2 + ni] = mfma16(AF[mi][ks], b23[ni][ks], acc[4 + mi][2 + ni]);
      const int ro = (mi * 16 + lr) * 64;
      AF[mi][0] = *(const s8v*)&lds[aBaseN + ro + xs0];
      AF[mi][1] = *(const s8v*)&lds[aBaseN + ro + xs1];
      SCHEDB;
    }
    __builtin_amdgcn_s_setprio(0);
  }
#undef GLOADA
#undef GLOADB

  // ---- epilogue ----
  const int rbase = mt * 256 + wrB + lg * 4;
  const int cbase = ntb * 256 + wcB + lr;
  if (EPI == 0) {
    u16* C = (u16*)Cv;
#pragma unroll
    for (int mi = 0; mi < 8; mi++)
#pragma unroll
      for (int ni = 0; ni < 4; ni++)
#pragma unroll
        for (int j = 0; j < 4; j++)
          C[(long)(rbase + mi * 16 + j) * N + (cbase + ni * 16)] = f2bf(acc[mi][ni][j]);
  } else if (EPI == 2) {
    u16* C = (u16*)Cv;
#pragma unroll
    for (int mi = 0; mi < 8; mi++)
#pragma unroll
      for (int ni = 0; ni < 4; ni++)
#pragma unroll
        for (int j = 0; j < 4; j++) {
          const int row = rbase + mi * 16 + j;
          const int col = cbase + ni * 16;
          C[(long)row * N + col] = f2bf(acc[mi][ni][j] + aux[((row & 15) << 12) | col]);
        }
  } else {
    float* C = (float*)Cv;
#pragma unroll
    for (int mi = 0; mi < 8; mi++)
#pragma unroll
      for (int ni = 0; ni < 4; ni++)
#pragma unroll
        for (int j = 0; j < 4; j++) {
          const int col = cbase + ni * 16;
          C[(long)(rbase + mi * 16 + j) * N + col] =
              (acc[mi][ni][j] + aux[col]) * RES_SCALE_;
        }
  }
}

// ---------------- generic 128x128 MFMA GEMM (small/medium shapes) ----------------
// EPI 1: f32 +bias[col].
template <int EPI>
__launch_bounds__(256)
__global__ void k_gemm(const u16* __restrict__ A, const u16* __restrict__ Bt,
                       void* __restrict__ Cv, const float* __restrict__ aux,
                       int M, int N, int K) {
  __shared__ u16 As[4096];
  __shared__ u16 Bs[4096];
  const int ntiles = N >> 7;
  const int mt = blockIdx.x / ntiles;
  const int nt = blockIdx.x % ntiles;
  const int tid = threadIdx.x;
  const int lane = tid & 63;
  const int w = tid >> 6;
  const int wr = w >> 1, wc = w & 1;
  const int lr = lane & 15, lg = lane >> 4;

  f4v acc[4][4];
#pragma unroll
  for (int m = 0; m < 4; m++)
#pragma unroll
    for (int n = 0; n < 4; n++) acc[m][n] = (f4v){0.f, 0.f, 0.f, 0.f};

  const u16* aSrc = A + (long)(mt * 128 + (tid >> 2)) * K + ((tid & 3) << 3);
  const u16* bSrc = Bt + (long)(nt * 128 + (tid >> 2)) * K + ((tid & 3) << 3);
  const long rowStep = (long)64 * K;

  const int kIters = K >> 5;
  for (int kb = 0; kb < kIters; kb++) {
    if (kb) __syncthreads();
    const u16* aP = aSrc + (kb << 5);
    const u16* bP = bSrc + (kb << 5);
    __builtin_amdgcn_global_load_lds((gas_p)aP, (las_p)&As[w * 512], 16, 0, 0);
    __builtin_amdgcn_global_load_lds((gas_p)(aP + rowStep), (las_p)&As[2048 + w * 512], 16, 0, 0);
    __builtin_amdgcn_global_load_lds((gas_p)bP, (las_p)&Bs[w * 512], 16, 0, 0);
    __builtin_amdgcn_global_load_lds((gas_p)(bP + rowStep), (las_p)&Bs[2048 + w * 512], 16, 0, 0);
    WAITVM0;
    __syncthreads();

    s8v af[4];
#pragma unroll
    for (int m = 0; m < 4; m++)
      af[m] = *(const s8v*)&As[(wr * 64 + m * 16 + lr) * 32 + (lg << 3)];
#pragma unroll
    for (int n = 0; n < 4; n++) {
      s8v bf = *(const s8v*)&Bs[(wc * 64 + n * 16 + lr) * 32 + (lg << 3)];
#pragma unroll
      for (int m = 0; m < 4; m++) acc[m][n] = mfma16(af[m], bf, acc[m][n]);
    }
  }

  const int rbase = mt * 128 + wr * 64 + lg * 4;
  const int cbase = nt * 128 + wc * 64 + lr;
  {
    float* C = (float*)Cv;
#pragma unroll
    for (int m = 0; m < 4; m++)
#pragma unroll
      for (int n = 0; n < 4; n++)
#pragma unroll
        for (int j = 0; j < 4; j++) {
          int row = rbase + m * 16 + j;
          int col = cbase + n * 16;
          C[(long)row * N + col] = acc[m][n][j] + aux[col];
        }
  }
}

// ---------------- smolgen MFMA layers ----------------

// z(32768x32 bf16) = xbf(32768x1024) @ ptwT(32x1024)^T + ptb
__launch_bounds__(256)
__global__ void k_smola_gemm(const u16* __restrict__ xbf, const u16* __restrict__ ptwT,
                             const float* __restrict__ ptb, u16* __restrict__ z) {
  const int rt = blockIdx.x;
  const int w = threadIdx.x >> 6, lane = threadIdx.x & 63;
  const int lr = lane & 15, lg = lane >> 4;
  const int row0 = rt * 64 + w * 16;
  f4v acc[2];
  acc[0] = (f4v){0.f, 0.f, 0.f, 0.f};
  acc[1] = (f4v){0.f, 0.f, 0.f, 0.f};
  const u16* aBase = xbf + (long)(row0 + lr) * 1024;
  const u16* bBase = ptwT + (long)lr * 1024;
#pragma unroll 4
  for (int k0 = 0; k0 < 1024; k0 += 32) {
    s8v a = *(const s8v*)&aBase[k0 + (lg << 3)];
#pragma unroll
    for (int n = 0; n < 2; n++) {
      s8v b = *(const s8v*)&bBase[(long)(n << 4) * 1024 + k0 + (lg << 3)];
      acc[n] = mfma16(a, b, acc[n]);
    }
  }
#pragma unroll
  for (int n = 0; n < 2; n++)
#pragma unroll
    for (int j = 0; j < 4; j++) {
      int col = (n << 4) + lr;
      z[(long)(row0 + lg * 4 + j) * 32 + col] = f2bf(acc[n][j] + ptb[col]);
    }
}

// uraw2(512x256 f32) = z(512x2048) @ pgwT(256x2048)^T + pgb
// [kept as a separate 128-block kernel: the 32-block fused GEMM+LN variant
//  measured +18.6µs — grid shrink 128->32 starves CUs on a latency-bound loop]
__launch_bounds__(64)
__global__ void k_smolb_gemm(const u16* __restrict__ z, const u16* __restrict__ pgwT,
                             const float* __restrict__ pgb, float* __restrict__ out) {
  const int bid = blockIdx.x;
  const int rt = bid >> 2, ct = bid & 3;
  const int lane = threadIdx.x;
  const int lr = lane & 15, lg = lane >> 4;
  f4v acc[4];
#pragma unroll
  for (int n = 0; n < 4; n++) acc[n] = (f4v){0.f, 0.f, 0.f, 0.f};
  const u16* aBase = z + (long)(rt * 16 + lr) * 2048;
  const u16* bBase = pgwT + (long)(ct * 64 + lr) * 2048;
#pragma unroll 4
  for (int k0 = 0; k0 < 2048; k0 += 32) {
    s8v a = *(const s8v*)&aBase[k0 + (lg << 3)];
#pragma unroll
    for (int n = 0; n < 4; n++) {
      s8v b = *(const s8v*)&bBase[(long)(n << 4) * 2048 + k0 + (lg << 3)];
      acc[n] = mfma16(a, b, acc[n]);
    }
  }
#pragma unroll
  for (int n = 0; n < 4; n++)
#pragma unroll
    for (int j = 0; j < 4; j++) {
      int row = rt * 16 + lg * 4 + j;
      int col = ct * 64 + (n << 4) + lr;
      out[(long)row * 256 + col] = acc[n][j] + pgb[col];
    }
}

// u = LN(silu(in)) per row of 256; in already has bias added. out bf16.
__launch_bounds__(64)
__global__ void k_ln2(const float* __restrict__ uraw, const float* __restrict__ g2,
                      const float* __restrict__ b2, u16* __restrict__ ubf) {
  const int row = blockIdx.x;
  const int lane = threadIdx.x;
  f4v x = *(const f4v*)&uraw[(long)row * 256 + lane * 4];
  float v[4];
  float s = 0.f, q = 0.f;
#pragma unroll
  for (int j = 0; j < 4; j++) {
    float xx = x[j];
    v[j] = xx / (1.f + __expf(-xx));
    s += v[j]; q += v[j] * v[j];
  }
#pragma unroll
  for (int mk = 1; mk < 64; mk <<= 1) { s += __shfl_xor(s, mk); q += __shfl_xor(q, mk); }
  float mean = s * (1.f / 256.f);
  float var = q * (1.f / 256.f) - mean * mean;
  float rs = rsqrtf(var + EPS_);
  u16x4 o;
  float o0 = (v[0] - mean) * rs * g2[lane * 4 + 0] + b2[lane * 4 + 0];
  float o1 = (v[1] - mean) * rs * g2[lane * 4 + 1] + b2[lane * 4 + 1];
  float o2 = (v[2] - mean) * rs * g2[lane * 4 + 2] + b2[lane * 4 + 2];
  float o3 = (v[3] - mean) * rs * g2[lane * 4 + 3] + b2[lane * 4 + 3];
  o.x = f2bf(o0); o.y = f2bf(o1); o.z = f2bf(o2); o.w = f2bf(o3);
  *(u16x4*)&ubf[(long)row * 256 + lane * 4] = o;
}

// ---------------- batched 64x64x64 MFMA kernels ----------------

// merged l2 + l3 (independent, same shape) — saves one launch gap.
__launch_bounds__(64)
__global__ void k_l23(const u16* __restrict__ qkv, const u16* __restrict__ aKb,
                      const u16* __restrict__ aQb, u16* __restrict__ l2b,
                      u16* __restrict__ l3a) {
  const int lane = threadIdx.x;
  const int lr = lane & 15, lg = lane >> 4;
  f4v acc[4][4];
#pragma unroll
  for (int m = 0; m < 4; m++)
#pragma unroll
    for (int n = 0; n < 4; n++) acc[m][n] = (f4v){0.f, 0.f, 0.f, 0.f};

  if (blockIdx.x < 8192) {
    const int bid = blockIdx.x;
    const int bt = bid & 7, t = (bid >> 3) & 63, h = bid >> 9;
    const u16* qb = qkv + (long)t * 3072 + h * 64;
    const u16* kb = aKb + ((long)h * 64 + t) * 4096;
#pragma unroll
    for (int ks = 0; ks < 2; ks++) {
      s8v a[4], bb[4];
#pragma unroll
      for (int m = 0; m < 4; m++) {
        int brow = bt * 64 + m * 16 + lr;
        a[m] = *(const s8v*)&qb[(long)brow * 196608 + ks * 32 + (lg << 3)];
      }
#pragma unroll
      for (int n = 0; n < 4; n++)
        bb[n] = *(const s8v*)&kb[(n * 16 + lr) * 64 + ks * 32 + (lg << 3)];
#pragma unroll
      for (int m = 0; m < 4; m++)
#pragma unroll
        for (int n = 0; n < 4; n++) acc[m][n] = mfma16(a[m], bb[n], acc[m][n]);
    }
    u16* dst = l2b + ((long)h * 64 + t) * 32768;  // + b*64 + s
#pragma unroll
    for (int m = 0; m < 4; m++)
#pragma unroll
      for (int n = 0; n < 4; n++)
#pragma unroll
        for (int j = 0; j < 4; j++) {
          int brow = bt * 64 + m * 16 + lg * 4 + j;
          int s = n * 16 + lr;
          dst[(long)brow * 64 + s] = f2bf(SCALE_ * acc[m][n][j]);
        }
  } else {
    const int bid = blockIdx.x - 8192;
    const int bt = bid & 7, s = (bid >> 3) & 63, h = bid >> 9;
    const u16* kb = qkv + (long)s * 3072 + 1024 + h * 64;
    const u16* qb = aQb + (long)h * 262144 + (long)s * 64;
#pragma unroll
    for (int ks = 0; ks < 2; ks++) {
      s8v a[4], bb[4];
#pragma unroll
      for (int m = 0; m < 4; m++) {
        int brow = bt * 64 + m * 16 + lr;
        a[m] = *(const s8v*)&kb[(long)brow * 196608 + ks * 32 + (lg << 3)];
      }
#pragma unroll
      for (int n = 0; n < 4; n++) {
        int tc = n * 16 + lr;
        bb[n] = *(const s8v*)&qb[(long)tc * 4096 + ks * 32 + (lg << 3)];
      }
#pragma unroll
      for (int m = 0; m < 4; m++)
#pragma unroll
        for (int n = 0; n < 4; n++) acc[m][n] = mfma16(a[m], bb[n], acc[m][n]);
    }
#pragma unroll
    for (int m = 0; m < 4; m++)
#pragma unroll
      for (int n = 0; n < 4; n++)
#pragma unroll
        for (int j = 0; j < 4; j++) {
          int brow = bt * 64 + m * 16 + lg * 4 + j;
          int tc = n * 16 + lr;
          long idx = (((long)brow * 16 + h) * 64 + s) * 64 + tc;
          l3a[idx] = f2bf(SCALE_ * acc[m][n][j]);
        }
  }
}

// out_heads[b,t,h,d] += sum_s attn[b,h,t,s]*aV[h,t,s,d];  grid h*512 + t*8 + bt
__launch_bounds__(64)
__global__ void k_c(const u16* __restrict__ attnb, const u16* __restrict__ aVt,
                    u16* __restrict__ outh) {
  const int bid = blockIdx.x;
  const int bt = bid & 7, t = (bid >> 3) & 63, h = bid >> 9;
  const int lane = threadIdx.x;
  const int lr = lane & 15, lg = lane >> 4;
  f4v acc[4][4];
#pragma unroll
  for (int m = 0; m < 4; m++)
#pragma unroll
    for (int n = 0; n < 4; n++) acc[m][n] = (f4v){0.f, 0.f, 0.f, 0.f};
  const u16* ab = attnb + ((long)h * 64 + t) * 64;      // + b*65536
  const u16* vb = aVt + ((long)h * 64 + t) * 4096;      // rows d, contiguous s
#pragma unroll
  for (int ks = 0; ks < 2; ks++) {
    s8v a[4], bb[4];
#pragma unroll
    for (int m = 0; m < 4; m++) {
      int brow = bt * 64 + m * 16 + lr;
      a[m] = *(const s8v*)&ab[(long)brow * 65536 + ks * 32 + (lg << 3)];
    }
#pragma unroll
    for (int n = 0; n < 4; n++)
      bb[n] = *(const s8v*)&vb[(n * 16 + lr) * 64 + ks * 32 + (lg << 3)];
#pragma unroll
    for (int m = 0; m < 4; m++)
#pragma unroll
      for (int n = 0; n < 4; n++) acc[m][n] = mfma16(a[m], bb[n], acc[m][n]);
  }
#pragma unroll
  for (int m = 0; m < 4; m++)
#pragma unroll
    for (int n = 0; n < 4; n++)
#pragma unroll
      for (int j = 0; j < 4; j++) {
        int brow = bt * 64 + m * 16 + lg * 4 + j;
        int d = n * 16 + lr;
        long idx = ((long)brow * 64 + t) * 1024 + h * 64 + d;
        outh[idx] = f2bf(bf2f(outh[idx]) + acc[m][n][j]);
      }
}

// ---------------- attention core: per (b,h) ----------------
// l3a slice staged COALESCED into Ps during the initial staging loop; the
// transposed [s][t] p-compute read comes from LDS (4x transaction amplification
// removed).  Pad 72 => 144B rows = 9x16B so staged s8v writes stay 16B-aligned;
// transposed u16x4 reads are 2-way bank-aliased (free).  Barrier count
// unchanged (first sync covers staging; pre-P-write sync protects Ps overwrite).
__launch_bounds__(256)
__global__ void k_attn(const u16* __restrict__ qkv, const u16* __restrict__ logits,
                       const u16* __restrict__ l2b, u16* __restrict__ l3a,
                       u16* __restrict__ outh) {
  __shared__ u16 Qs[64 * 72];
  __shared__ u16 Ks[64 * 72];
  __shared__ u16 Vt[64 * 72];
  __shared__ u16 Ps[64 * 72];   // staged l3a slice first, then P
  const int bh = blockIdx.x;
  const int b = bh >> 4, h = bh & 15;
  const int tid = threadIdx.x;
  const int lane = tid & 63, w = tid >> 6;
  const int lr = lane & 15, lg = lane >> 4;
  const u16* qbase = qkv + (long)b * 196608 + h * 64;
  const long base = (long)bh * 4096;

#pragma unroll
  for (int c = 0; c < 2; c++) {
    int flat = c * 2048 + tid * 8;
    int row = flat >> 6, k = flat & 63;
    const u16* src = &qbase[(long)row * 3072 + k];
    *(s8v*)&Qs[row * 72 + k] = *(const s8v*)(src);
    *(s8v*)&Ks[row * 72 + k] = *(const s8v*)(src + 1024);
    s8v v = *(const s8v*)(src + 2048);
#pragma unroll
    for (int j = 0; j < 8; j++) Vt[(k + j) * 72 + row] = (u16)v[j];
    // coalesced l3a staging: Ps[s][t] mirrors global [s-major] layout
    *(s8v*)&Ps[row * 72 + k] = *(const s8v*)&l3a[base + flat];
  }
  __syncthreads();

  f4v sacc[4];
#pragma unroll
  for (int n = 0; n < 4; n++) sacc[n] = (f4v){0.f, 0.f, 0.f, 0.f};
#pragma unroll
  for (int ks = 0; ks < 2; ks++) {
    s8v a = *(const s8v*)&Qs[(w * 16 + lr) * 72 + ks * 32 + (lg << 3)];
#pragma unroll
    for (int n = 0; n < 4; n++) {
      s8v bb = *(const s8v*)&Ks[(n * 16 + lr) * 72 + ks * 32 + (lg << 3)];
      sacc[n] = mfma16(a, bb, sacc[n]);
    }
  }

  const int r0 = w * 16 + lg * 4;
  float p[4][4];
#pragma unroll
  for (int n = 0; n < 4; n++) {
    int s = n * 16 + lr;
    u16x4 l3v = *(const u16x4*)&Ps[s * 72 + r0];   // LDS (staged l3a)
#pragma unroll
    for (int j = 0; j < 4; j++) {
      float l3f = bf2f(((const u16*)&l3v)[j]);
      float l2f = bf2f(l2b[(((long)h * 64 + r0 + j) * 512 + b) * 64 + s]);
      float lgf = bf2f(logits[base + (r0 + j) * 64 + s]);
      p[n][j] = sacc[n][j] * SCALE_ + lgf + l3f + l2f;
    }
  }
#pragma unroll
  for (int j = 0; j < 4; j++) {
    float m = fmaxf(fmaxf(p[0][j], p[1][j]), fmaxf(p[2][j], p[3][j]));
    m = fmaxf(m, __shfl_xor(m, 1));
    m = fmaxf(m, __shfl_xor(m, 2));
    m = fmaxf(m, __shfl_xor(m, 4));
    m = fmaxf(m, __shfl_xor(m, 8));
    float s0 = 0.f;
#pragma unroll
    for (int n = 0; n < 4; n++) { p[n][j] = __expf(p[n][j] - m); s0 += p[n][j]; }
    s0 += __shfl_xor(s0, 1);
    s0 += __shfl_xor(s0, 2);
    s0 += __shfl_xor(s0, 4);
    s0 += __shfl_xor(s0, 8);
    float inv = 1.f / s0;
#pragma unroll
    for (int n = 0; n < 4; n++) p[n][j] *= inv;
  }

  // All Ps-as-l3a reads complete in every thread past this barrier; safe to
  // overwrite Ps with P (and l3a global with P for k_c).
  __syncthreads();

#pragma unroll
  for (int n = 0; n < 4; n++) {
    int s = n * 16 + lr;
#pragma unroll
    for (int j = 0; j < 4; j++) {
      u16 pb = f2bf(p[n][j]);
      l3a[base + (r0 + j) * 64 + s] = pb;
      Ps[(r0 + j) * 72 + s] = pb;
    }
  }
  __syncthreads();

  f4v oacc[4];
#pragma unroll
  for (int n = 0; n < 4; n++) oacc[n] = (f4v){0.f, 0.f, 0.f, 0.f};
#pragma unroll
  for (int ks = 0; ks < 2; ks++) {
    s8v a = *(const s8v*)&Ps[(w * 16 + lr) * 72 + ks * 32 + (lg << 3)];
#pragma unroll
    for (int n = 0; n < 4; n++) {
      s8v vb = *(const s8v*)&Vt[(n * 16 + lr) * 72 + ks * 32 + (lg << 3)];
      oacc[n] = mfma16(a, vb, oacc[n]);
    }
  }
  u16* obase = outh + (long)b * 65536 + h * 64;
#pragma unroll
  for (int n = 0; n < 4; n++)
#pragma unroll
    for (int j = 0; j < 4; j++)
      obase[(long)(r0 + j) * 1024 + n * 16 + lr] = f2bf(oacc[n][j]);
}

// ---------------- launcher ----------------

extern "C" void kernel_launch(void* const* d_in, const int* in_sizes, int n_in,
                              void* d_out, int out_size, void* d_ws, size_t ws_size,
                              hipStream_t stream) {
  (void)in_sizes; (void)n_in;
  const float* x    = (const float*)d_in[0];
  const float* Wq   = (const float*)d_in[1];
  const float* Wk   = (const float*)d_in[2];
  const float* Wv   = (const float*)d_in[3];
  const float* Wo_w = (const float*)d_in[4];
  const float* Wo_b = (const float*)d_in[5];
  const float* sb   = (const float*)d_in[6];
  const float* aQ   = (const float*)d_in[7];
  const float* aK   = (const float*)d_in[8];
  const float* aV   = (const float*)d_in[9];
  const float* pt_w = (const float*)d_in[10];
  const float* pt_b = (const float*)d_in[11];
  const float* pg_w = (const float*)d_in[12];
  const float* pg_b = (const float*)d_in[13];
  const float* ph_w = (const float*)d_in[14];
  const float* ph_b = (const float*)d_in[15];
  const float* ln1g = (const float*)d_in[16];
  const float* ln1b = (const float*)d_in[17];
  const float* ln2g = (const float*)d_in[18];
  const float* ln2b = (const float*)d_in[19];
  const float* shw  = (const float*)d_in[20];

  char* wsp = (char*)d_ws;
  size_t off = 0;
  auto alloc = [&](size_t bytes) {
    void* p = wsp + off;
    off += (bytes + 255) & ~(size_t)255;
    return p;
  };
  u16*   xbf    = (u16*)alloc(33554432ull * 2);    // also reused as outh
  u16*   qkv    = (u16*)alloc(100663296ull * 2);   // 32768 x 3072
  u16*   logits = (u16*)alloc(33554432ull * 2);    // (B,H,T,S) bf16 (smolgen+extra)
  u16*   l3a    = (u16*)alloc(33554432ull * 2);    // l3 term, then attn probs
  u16*   l2b    = (u16*)alloc(33554432ull * 2);    // l2 term (h,t,b,s)
  u16*   Wqkvt  = (u16*)alloc(3145728ull * 2);     // 3072 x 1024
  u16*   Wot    = (u16*)alloc(1048576ull * 2);
  u16*   phwt   = (u16*)alloc(1048576ull * 2);     // 4096 x 256
  u16*   swt    = (u16*)alloc(1048576ull * 2);     // 4096 x 256
  u16*   aKb    = (u16*)alloc(4194304ull * 2);
  u16*   aQb    = (u16*)alloc(4194304ull * 2);
  u16*   aVt    = (u16*)alloc(4194304ull * 2);
  float* extra  = (float*)alloc(65536ull * 4);
  u16*   z      = (u16*)alloc(1048576ull * 2);     // 32768 x 32
  u16*   g      = (u16*)alloc(131072ull * 2);      // 512 x 256
  float* uraw   = (float*)alloc(2097152ull * 4);   // 512 x 4096
  u16*   ubf    = (u16*)alloc(2097152ull * 2);     // 8192 x 256
  u16*   ptwT   = (u16*)alloc(32768ull * 2);       // 32 x 1024
  u16*   pgwT   = (u16*)alloc(524288ull * 2);      // 256 x 2048
  float* uraw2  = (float*)alloc(131072ull * 4);    // 512 x 256
  u16*   outh   = xbf;                             // alias: xbf dead after smolgen A
  float* dout   = (float*)d_out;

  if (off > ws_size) {
    fprintf(stderr, "[kernel_launch] insufficient workspace: need %zu have %zu\n",
            off, ws_size);
    k_zero<<<2048, 256, 0, stream>>>(dout, (long)out_size);
    return;
  }

  // all independent input prep in one launch
  k_prep<<<6144, 256, 0, stream>>>(x, xbf, Wq, Wk, Wv, Wo_w, Wqkvt, Wot,
                                   ph_w, phwt, shw, swt, pg_w, pgwT, pt_w, ptwT,
                                   aK, aKb, aQ, aQb, aV, aVt, sb, extra);

  k_gemm256<0><<<1536, 512, 0, stream>>>(xbf, Wqkvt, qkv, nullptr, 32768, 3072, 1024);

  k_smola_gemm<<<512, 256, 0, stream>>>(xbf, ptwT, pt_b, z);
  k_smolb_gemm<<<128, 64, 0, stream>>>(z, pgwT, pg_b, uraw2);
  k_ln2<<<512, 64, 0, stream>>>(uraw2, ln1g, ln1b, g);
  k_gemm<1><<<128, 256, 0, stream>>>(g, phwt, uraw, ph_b, 512, 4096, 256);
  k_ln2<<<8192, 64, 0, stream>>>(uraw, ln2g, ln2b, ubf);
  k_gemm256<2><<<512, 512, 0, stream>>>(ubf, swt, logits, extra, 8192, 4096, 256);

  k_l23<<<16384, 64, 0, stream>>>(qkv, aKb, aQb, l2b, l3a);
  k_attn<<<8192, 256, 0, stream>>>(qkv, logits, l2b, l3a, outh);
  k_c<<<8192, 64, 0, stream>>>(l3a, aVt, outh);
  k_gemm256<3><<<512, 512, 0, stream>>>(outh, Wot, dout, Wo_b, 32768, 1024, 1024);
}